// Round 9
// baseline (211.801 us; speedup 1.0000x reference)
//
#include <hip/hip_runtime.h>

#define K1N 10
#define K2N 10
#define MMN 50

typedef __attribute__((ext_vector_type(8))) short short8;
typedef __attribute__((ext_vector_type(4))) float f32x4;

__device__ __forceinline__ float fast_tanh(float x) {
  x = fminf(fmaxf(x, -15.f), 15.f);
  float e2 = __expf(2.f * x);
  return (e2 - 1.f) * __builtin_amdgcn_rcpf(e2 + 1.f);
}

// reference's _avg_on_real_neighbor weight (exact f32 semantics)
__device__ __forceinline__ float nb_w(float cnt) {
  float w = 1.0f / (cnt + 1e-8f);
  return (w >= 1e8f) ? 0.f : w;
}

// f32 -> bf16 RNE as raw ushort; exact bf16 -> f32
__device__ __forceinline__ unsigned short f2bf(float x) {
  unsigned u = __builtin_bit_cast(unsigned, x);
  return (unsigned short)((u + 0x7FFFu + ((u >> 16) & 1u)) >> 16);
}
__device__ __forceinline__ float bf2f(unsigned short s) {
  return __builtin_bit_cast(float, ((unsigned)s) << 16);
}

__device__ __forceinline__ void fma4(float& y, float4 w, float4 x) {
  y = fmaf(w.x, x.x, y);
  y = fmaf(w.y, x.y, y);
  y = fmaf(w.z, x.z, y);
  y = fmaf(w.w, x.w, y);
}

// stage 64x64 f32 into LDS, XOR-swizzled float4 chunks (final kernel)
__device__ __forceinline__ void stage_w(const float* __restrict__ W, float* lds, int tid) {
  const float4* src = reinterpret_cast<const float4*>(W);
  float4* dst = reinterpret_cast<float4*>(lds);
#pragma unroll
  for (int i = 0; i < 4; ++i) {
    int c = tid + i * 256;
    int e = c >> 4, q = c & 15;
    dst[(e << 4) | (q ^ (e & 7))] = src[c];
  }
}

#define MFMA16(A, B, C) __builtin_amdgcn_mfma_f32_16x16x32_bf16(A, B, C, 0, 0, 0)

// one phase-1 k-chunk: 16 MFMA rows, row u = bi*4+kq (bi=u>>2, kq=u&3), kq<KQ valid.
// Wave-wide coalesced gathers (lane = dim), X via per-wave swizzled LDS planes.
// X planes: {t1-hi, t1-lo, t2-hi} (t2-lo dropped: ~1e-6 rms contribution).
template <int KQ>
__device__ __forceinline__ void p1_step(
    int kbase, int b0w, int lane, int g, int r15,
    const int* __restrict__ dsd1, const int* __restrict__ dsd2,
    const float* __restrict__ symp, const float* __restrict__ dise,
    const unsigned short* __restrict__ Wl0, const unsigned short* __restrict__ Wl1,
    unsigned short* xw, const short8 (&Bh)[2][4][2],
    float (&s1sum)[4], float& c1f) {
  // ---- gather + 3-plane X writes (single pass) ----
#pragma unroll
  for (int u = 0; u < 16; ++u) {
    if ((u & 3) >= KQ) continue;
    const int b = b0w + (u >> 2);
    const int k = kbase + (u & 3);
    const int sidx = dsd1[b * K1N + k];         // wave-uniform -> s_load
    float es = symp[(sidx << 6) | lane];        // coalesced full row
    const int* dp = dsd2 + (b * K1N + k) * K2N; // wave-uniform -> s_load
    float acc = 0.f;
    int c2 = 0;
#pragma unroll
    for (int j = 0; j < K2N; ++j) {
      int dj = dp[j];
      c2 += (dj != 0);
      acc += dise[(dj << 6) | lane];            // dise row 0 is exactly zero
    }
    float w2 = (c2 == 0) ? 0.f : __builtin_amdgcn_rcpf((float)c2 + 1e-8f);
    float ad = acc * w2;
    float t1 = es + ad, t2 = es * ad;
    c1f += ((g == (u >> 2)) && (sidx != 0)) ? 1.f : 0.f;
    const int off = u * 64 + (((lane >> 3) ^ (u & 7)) << 3) + (lane & 7);
    unsigned short hh = f2bf(t1);
    xw[off] = hh;
    xw[1024 + off] = f2bf(t1 - bf2f(hh));
    xw[2048 + off] = f2bf(t2);
  }
  asm volatile("s_waitcnt lgkmcnt(0)" ::: "memory");  // own-wave X writes visible

  // ---- MFMA: Y = X1*W21^T + X2*W22^T, bf16 split; hi from regs, lo from LDS ----
  f32x4 acc4[4];
#pragma unroll
  for (int nt = 0; nt < 4; ++nt) acc4[nt] = (f32x4){0.f, 0.f, 0.f, 0.f};
#pragma unroll
  for (int ks = 0; ks < 2; ++ks) {
    const int aoff = r15 * 64 + (((4 * ks + g) ^ (r15 & 7)) << 3);
    short8 a1h = *(const short8*)(xw + aoff);
    short8 a1l = *(const short8*)(xw + 1024 + aoff);
    short8 a2h = *(const short8*)(xw + 2048 + aoff);
#pragma unroll
    for (int nt = 0; nt < 4; ++nt) {
      const int wb = (nt * 16 + r15) * 64 + (((4 * ks + g) ^ (r15 & 7)) << 3);
      short8 w21l = *(const short8*)(Wl0 + wb);
      short8 w22l = *(const short8*)(Wl1 + wb);
      acc4[nt] = MFMA16(a1h, Bh[0][nt][ks], acc4[nt]);
      acc4[nt] = MFMA16(a1l, Bh[0][nt][ks], acc4[nt]);
      acc4[nt] = MFMA16(a1h, w21l, acc4[nt]);
      acc4[nt] = MFMA16(a2h, Bh[1][nt][ks], acc4[nt]);
      acc4[nt] = MFMA16(a2h, w22l, acc4[nt]);
    }
  }
  // ---- epilogue: rows 4g+rr belong to elem g (kq=rr); tanh + l2norm ----
#pragma unroll
  for (int rr = 0; rr < KQ; ++rr) {
    float ta[4], ss = 0.f;
#pragma unroll
    for (int nt = 0; nt < 4; ++nt) {
      ta[nt] = fast_tanh(acc4[nt][rr]);
      ss = fmaf(ta[nt], ta[nt], ss);
    }
    ss += __shfl_xor(ss, 1, 64); ss += __shfl_xor(ss, 2, 64);
    ss += __shfl_xor(ss, 4, 64); ss += __shfl_xor(ss, 8, 64);
    float inv = __builtin_amdgcn_rcpf(fmaxf(sqrtf(ss), 1e-12f));
#pragma unroll
    for (int nt = 0; nt < 4; ++nt) s1sum[nt] = fmaf(ta[nt], inv, s1sum[nt]);
  }
}

// ============ phase 1: 4 waves/block, wave = 4 elems, 40 KB LDS -> 4 blocks/CU ============
// launch_bounds (256,3): lets regalloc settle at ~84 VGPR (<=128 still allows 4 waves/SIMD);
// (256,4) capped VGPR at 64 and spilled 50 MB (round-8 regression).
__global__ __launch_bounds__(256, 3) void hgnn_phase1(
    const int* __restrict__ dsd1, const int* __restrict__ dsd2,
    const float* __restrict__ symp, const float* __restrict__ dise,
    const float* __restrict__ W21, const float* __restrict__ W22,
    float* __restrict__ s1avg) {
  __shared__ unsigned short Wl[2][4096];     // {w21lo, w22lo} swizzled bf16 planes (16 KB)
  __shared__ unsigned short Xs[4][3][1024];  // per-wave {t1h,t1l,t2h} (24 KB)
  const int tid = threadIdx.x;
  const int lane = tid & 63;
  const int wv = __builtin_amdgcn_readfirstlane(tid >> 6);
  const int g = lane >> 4, r15 = lane & 15;

  // stage W lo planes: 1024 16B-chunks, 4/thread
#pragma unroll
  for (int i = 0; i < 4; ++i) {
    int c = tid + (i << 8);
    int pl = c >> 9, rc = c & 511;
    int row = rc >> 3, ch = rc & 7;
    const float* src = (pl ? W22 : W21) + row * 64 + ch * 8;
    short8 v;
#pragma unroll
    for (int j = 0; j < 8; ++j) {
      float w = src[j];
      v[j] = (short)f2bf(w - bf2f(f2bf(w)));
    }
    *reinterpret_cast<short8*>(&Wl[pl][row * 64 + ((ch ^ (row & 7)) << 3)]) = v;
  }
  // W21/W22 hi B-frags into 64 VGPRs
  short8 Bh[2][4][2];
#pragma unroll
  for (int mat = 0; mat < 2; ++mat) {
    const float* Wm = mat ? W22 : W21;
#pragma unroll
    for (int nt = 0; nt < 4; ++nt)
#pragma unroll
      for (int ks = 0; ks < 2; ++ks) {
        const float4* p = reinterpret_cast<const float4*>(Wm + (nt * 16 + r15) * 64 + ks * 32 + g * 8);
        float4 va = p[0], vb = p[1];
        short8 h;
        h[0] = (short)f2bf(va.x); h[1] = (short)f2bf(va.y);
        h[2] = (short)f2bf(va.z); h[3] = (short)f2bf(va.w);
        h[4] = (short)f2bf(vb.x); h[5] = (short)f2bf(vb.y);
        h[6] = (short)f2bf(vb.z); h[7] = (short)f2bf(vb.w);
        Bh[mat][nt][ks] = h;
      }
  }
  __syncthreads();

  const int b0w = blockIdx.x * 16 + wv * 4;
  unsigned short* xw = &Xs[wv][0][0];
  float s1sum[4] = {0.f, 0.f, 0.f, 0.f};
  float c1f = 0.f;

  p1_step<4>(0, b0w, lane, g, r15, dsd1, dsd2, symp, dise, Wl[0], Wl[1], xw, Bh, s1sum, c1f);
  p1_step<4>(4, b0w, lane, g, r15, dsd1, dsd2, symp, dise, Wl[0], Wl[1], xw, Bh, s1sum, c1f);
  p1_step<2>(8, b0w, lane, g, r15, dsd1, dsd2, symp, dise, Wl[0], Wl[1], xw, Bh, s1sum, c1f);

  // c1f is uniform within each g-group; elem = b0w + g, cols d = nt*16 + r15
  float w1 = nb_w(c1f);
  float* dst = s1avg + (size_t)(b0w + g) * 64 + r15;
#pragma unroll
  for (int nt = 0; nt < 4; ++nt) dst[nt * 16] = s1sum[nt] * w1;
}

// ============ usu gather-average: quad-row loads (4 symp rows per instruction) ============
__global__ __launch_bounds__(256, 8) void hgnn_usu_avg(
    const int* __restrict__ usu1, const float* __restrict__ symp,
    float* __restrict__ mu) {
  const int tid = threadIdx.x;
  const int lane = tid & 63;
  const int wv = __builtin_amdgcn_readfirstlane(tid >> 6);
  const int grp = lane >> 4;
  const int d4 = (lane & 15) << 2;  // this lane's 4-dim slice
  const int b0 = blockIdx.x * 16 + wv * 4;

#pragma unroll
  for (int e = 0; e < 4; ++e) {
    const int b = b0 + e;
    int ui = 0;
    if (lane < MMN) ui = usu1[b * MMN + lane];
    float cnt = (float)__popcll(__ballot(ui != 0));
    f32x4 su = {0.f, 0.f, 0.f, 0.f};
    // 12 quad-iters cover m=0..47 (group grp takes m+grp); tail covers 48,49
#pragma unroll
    for (int m = 0; m < 48; m += 4) {
      int idx = __shfl(ui, m + grp, 64);
      su += *(const f32x4*)(symp + (idx << 6) + d4);  // symp row 0 is exactly zero
    }
    {
      int idx = __shfl(ui, 48 + grp, 64);
      if (grp < 2) su += *(const f32x4*)(symp + (idx << 6) + d4);
    }
#pragma unroll
    for (int c = 0; c < 4; ++c) {
      su[c] += __shfl_xor(su[c], 16, 64);
      su[c] += __shfl_xor(su[c], 32, 64);
    }
    float w = nb_w(cnt);
    if (lane < 16) {
      f32x4 r = su * w;
      *reinterpret_cast<f32x4*>(mu + (size_t)b * 64 + d4) = r;
    }
  }
}

// ================= final: label gather + 3 matvecs + dot (proven round-3 kernel) =================
__global__ __launch_bounds__(256, 2) void hgnn_final(
    const int* __restrict__ label, const float* __restrict__ dise,
    const float* __restrict__ W11, const float* __restrict__ W12,
    const float* __restrict__ Wu,
    const float* __restrict__ s1avg, const float* __restrict__ mu,
    float* __restrict__ out) {
  __shared__ float lw[3][4096];
  __shared__ float xb[4][4][3][64];
  const int tid = threadIdx.x;
  const int lane = tid & 63;
  const int wv = __builtin_amdgcn_readfirstlane(tid >> 6);
  stage_w(W11, lw[0], tid);
  stage_w(W12, lw[1], tid);
  stage_w(Wu, lw[2], tid);
  __syncthreads();

  const int b0 = blockIdx.x * 16 + wv * 4;
#pragma unroll
  for (int bi = 0; bi < 4; ++bi) {
    const int b = b0 + bi;
    float s1 = s1avg[(size_t)b * 64 + lane];
    float mv = mu[(size_t)b * 64 + lane];
    int lb = label[b];
    float t = dise[(lb << 6) | lane];
    xb[wv][bi][0][lane] = s1 + t;
    xb[wv][bi][1][lane] = s1 * t;
    xb[wv][bi][2][lane] = mv;
  }
  asm volatile("s_waitcnt lgkmcnt(0)" ::: "memory");

  float y1[4] = {0.f, 0.f, 0.f, 0.f};
  float y2[4] = {0.f, 0.f, 0.f, 0.f};
  const int swz = lane & 7;
#pragma unroll 4
  for (int q = 0; q < 16; ++q) {
    float4 wa = reinterpret_cast<float4*>(lw[0])[(lane << 4) | (q ^ swz)];
    float4 wb = reinterpret_cast<float4*>(lw[1])[(lane << 4) | (q ^ swz)];
    float4 wc = reinterpret_cast<float4*>(lw[2])[(lane << 4) | (q ^ swz)];
#pragma unroll
    for (int bi = 0; bi < 4; ++bi) {
      float4 xv1 = *reinterpret_cast<const float4*>(&xb[wv][bi][0][q << 2]);
      float4 xv2 = *reinterpret_cast<const float4*>(&xb[wv][bi][1][q << 2]);
      float4 xv3 = *reinterpret_cast<const float4*>(&xb[wv][bi][2][q << 2]);
      fma4(y1[bi], wa, xv1);
      fma4(y1[bi], wb, xv2);
      fma4(y2[bi], wc, xv3);
    }
  }
#pragma unroll
  for (int bi = 0; bi < 4; ++bi) {
    float ed = fast_tanh(y1[bi]);
    float eu = fast_tanh(y2[bi]);
    float p = ed * eu;
#pragma unroll
    for (int off = 32; off; off >>= 1) p += __shfl_xor(p, off, 64);
    if (lane == 0) out[b0 + bi] = p;
  }
}

extern "C" void kernel_launch(void* const* d_in, const int* in_sizes, int n_in,
                              void* d_out, int out_size, void* d_ws, size_t ws_size,
                              hipStream_t stream) {
  const int* dsd1 = (const int*)d_in[0];
  const int* dsd2 = (const int*)d_in[1];
  const int* usu1 = (const int*)d_in[2];
  const int* label = (const int*)d_in[3];
  const float* symp = (const float*)d_in[4];
  const float* dise = (const float*)d_in[5];
  const float* Wu = (const float*)d_in[6];
  const float* W21 = (const float*)d_in[7];
  const float* W22 = (const float*)d_in[8];
  const float* W11 = (const float*)d_in[9];
  const float* W12 = (const float*)d_in[10];
  float* out = (float*)d_out;

  const int B = in_sizes[3];
  float* s1 = (float*)d_ws;         // B*64 f32 = 4 MB
  float* mu = s1 + (size_t)B * 64;  // B*64 f32 = 4 MB

  hipLaunchKernelGGL(hgnn_phase1, dim3(B / 16), dim3(256), 0, stream,
                     dsd1, dsd2, symp, dise, W21, W22, s1);
  hipLaunchKernelGGL(hgnn_usu_avg, dim3(B / 16), dim3(256), 0, stream,
                     usu1, symp, mu);
  hipLaunchKernelGGL(hgnn_final, dim3(B / 16), dim3(256), 0, stream,
                     label, dise, W11, W12, Wu, s1, mu, out);
}

// Round 10
// 112.938 us; speedup vs baseline: 1.8754x; 1.8754x over previous
//
#include <hip/hip_runtime.h>

#define K1N 10
#define K2N 10
#define MMN 50

typedef __attribute__((ext_vector_type(8))) short short8;
typedef __attribute__((ext_vector_type(4))) float f32x4;

__device__ __forceinline__ float fast_tanh(float x) {
  x = fminf(fmaxf(x, -15.f), 15.f);
  float e2 = __expf(2.f * x);
  return (e2 - 1.f) * __builtin_amdgcn_rcpf(e2 + 1.f);
}

// reference's _avg_on_real_neighbor weight (exact f32 semantics)
__device__ __forceinline__ float nb_w(float cnt) {
  float w = 1.0f / (cnt + 1e-8f);
  return (w >= 1e8f) ? 0.f : w;
}

// f32 -> bf16 RNE as raw ushort; exact bf16 -> f32
__device__ __forceinline__ unsigned short f2bf(float x) {
  unsigned u = __builtin_bit_cast(unsigned, x);
  return (unsigned short)((u + 0x7FFFu + ((u >> 16) & 1u)) >> 16);
}
__device__ __forceinline__ float bf2f(unsigned short s) {
  return __builtin_bit_cast(float, ((unsigned)s) << 16);
}

__device__ __forceinline__ void fma4(float& y, float4 w, float4 x) {
  y = fmaf(w.x, x.x, y);
  y = fmaf(w.y, x.y, y);
  y = fmaf(w.z, x.z, y);
  y = fmaf(w.w, x.w, y);
}

// stage 64x64 f32 into LDS, XOR-swizzled float4 chunks (final kernel)
__device__ __forceinline__ void stage_w(const float* __restrict__ W, float* lds, int tid) {
  const float4* src = reinterpret_cast<const float4*>(W);
  float4* dst = reinterpret_cast<float4*>(lds);
#pragma unroll
  for (int i = 0; i < 4; ++i) {
    int c = tid + i * 256;
    int e = c >> 4, q = c & 15;
    dst[(e << 4) | (q ^ (e & 7))] = src[c];
  }
}

#define MFMA16(A, B, C) __builtin_amdgcn_mfma_f32_16x16x32_bf16(A, B, C, 0, 0, 0)

// one phase-1 k-chunk: 16 MFMA rows, row u = bi*4+kq (bi=u>>2, kq=u&3), kq<KQ valid.
// Wave-wide coalesced gathers (lane = dim), X via per-wave swizzled LDS planes.
// ROUND-7 PROVEN VERSION: 4 X planes {t1h,t1l,t2h,t2l}, 6 MFMAs per (ks,nt).
template <int KQ>
__device__ __forceinline__ void p1_step(
    int kbase, int b0w, int lane, int g, int r15,
    const int* __restrict__ dsd1, const int* __restrict__ dsd2,
    const float* __restrict__ symp, const float* __restrict__ dise,
    const unsigned short* __restrict__ Wl0, const unsigned short* __restrict__ Wl1,
    unsigned short* xw, const short8 (&Bh)[2][4][2],
    float (&s1sum)[4], float& c1f) {
  // ---- gather + 4-plane X writes (single pass) ----
#pragma unroll
  for (int u = 0; u < 16; ++u) {
    if ((u & 3) >= KQ) continue;
    const int b = b0w + (u >> 2);
    const int k = kbase + (u & 3);
    const int sidx = dsd1[b * K1N + k];         // wave-uniform -> s_load
    float es = symp[(sidx << 6) | lane];        // coalesced full row
    const int* dp = dsd2 + (b * K1N + k) * K2N; // wave-uniform -> s_load
    float acc = 0.f;
    int c2 = 0;
#pragma unroll
    for (int j = 0; j < K2N; ++j) {
      int dj = dp[j];
      c2 += (dj != 0);
      acc += dise[(dj << 6) | lane];            // dise row 0 is exactly zero
    }
    float w2 = (c2 == 0) ? 0.f : __builtin_amdgcn_rcpf((float)c2 + 1e-8f);
    float ad = acc * w2;
    float t1 = es + ad, t2 = es * ad;
    c1f += ((g == (u >> 2)) && (sidx != 0)) ? 1.f : 0.f;
    const int off = u * 64 + (((lane >> 3) ^ (u & 7)) << 3) + (lane & 7);
    unsigned short hh;
    hh = f2bf(t1); xw[off] = hh; xw[1024 + off] = f2bf(t1 - bf2f(hh));
    hh = f2bf(t2); xw[2048 + off] = hh; xw[3072 + off] = f2bf(t2 - bf2f(hh));
  }
  asm volatile("s_waitcnt lgkmcnt(0)" ::: "memory");  // own-wave X writes visible

  // ---- MFMA: Y = X1*W21^T + X2*W22^T, 3-term bf16 split; hi from regs, lo from LDS ----
  f32x4 acc4[4];
#pragma unroll
  for (int nt = 0; nt < 4; ++nt) acc4[nt] = (f32x4){0.f, 0.f, 0.f, 0.f};
#pragma unroll
  for (int ks = 0; ks < 2; ++ks) {
    const int aoff = r15 * 64 + (((4 * ks + g) ^ (r15 & 7)) << 3);
    short8 a1h = *(const short8*)(xw + aoff);
    short8 a1l = *(const short8*)(xw + 1024 + aoff);
    short8 a2h = *(const short8*)(xw + 2048 + aoff);
    short8 a2l = *(const short8*)(xw + 3072 + aoff);
#pragma unroll
    for (int nt = 0; nt < 4; ++nt) {
      const int wb = (nt * 16 + r15) * 64 + (((4 * ks + g) ^ (r15 & 7)) << 3);
      short8 w21l = *(const short8*)(Wl0 + wb);
      short8 w22l = *(const short8*)(Wl1 + wb);
      acc4[nt] = MFMA16(a1h, Bh[0][nt][ks], acc4[nt]);
      acc4[nt] = MFMA16(a1l, Bh[0][nt][ks], acc4[nt]);
      acc4[nt] = MFMA16(a1h, w21l, acc4[nt]);
      acc4[nt] = MFMA16(a2h, Bh[1][nt][ks], acc4[nt]);
      acc4[nt] = MFMA16(a2l, Bh[1][nt][ks], acc4[nt]);
      acc4[nt] = MFMA16(a2h, w22l, acc4[nt]);
    }
  }
  // ---- epilogue: rows 4g+rr belong to elem g (kq=rr); tanh + l2norm ----
#pragma unroll
  for (int rr = 0; rr < KQ; ++rr) {
    float ta[4], ss = 0.f;
#pragma unroll
    for (int nt = 0; nt < 4; ++nt) {
      ta[nt] = fast_tanh(acc4[nt][rr]);
      ss = fmaf(ta[nt], ta[nt], ss);
    }
    ss += __shfl_xor(ss, 1, 64); ss += __shfl_xor(ss, 2, 64);
    ss += __shfl_xor(ss, 4, 64); ss += __shfl_xor(ss, 8, 64);
    float inv = __builtin_amdgcn_rcpf(fmaxf(sqrtf(ss), 1e-12f));
#pragma unroll
    for (int nt = 0; nt < 4; ++nt) s1sum[nt] = fmaf(ta[nt], inv, s1sum[nt]);
  }
}

// ============ phase 1: 4 waves/block, wave = 4 elems, 48 KB LDS (round-7 proven config) ============
__global__ __launch_bounds__(256, 3) void hgnn_phase1(
    const int* __restrict__ dsd1, const int* __restrict__ dsd2,
    const float* __restrict__ symp, const float* __restrict__ dise,
    const float* __restrict__ W21, const float* __restrict__ W22,
    float* __restrict__ s1avg) {
  __shared__ unsigned short Wl[2][4096];     // {w21lo, w22lo} swizzled bf16 planes (16 KB)
  __shared__ unsigned short Xs[4][4][1024];  // per-wave {t1h,t1l,t2h,t2l} (32 KB)
  const int tid = threadIdx.x;
  const int lane = tid & 63;
  const int wv = __builtin_amdgcn_readfirstlane(tid >> 6);
  const int g = lane >> 4, r15 = lane & 15;

  // stage W lo planes: 1024 16B-chunks, 4/thread
#pragma unroll
  for (int i = 0; i < 4; ++i) {
    int c = tid + (i << 8);
    int pl = c >> 9, rc = c & 511;
    int row = rc >> 3, ch = rc & 7;
    const float* src = (pl ? W22 : W21) + row * 64 + ch * 8;
    short8 v;
#pragma unroll
    for (int j = 0; j < 8; ++j) {
      float w = src[j];
      v[j] = (short)f2bf(w - bf2f(f2bf(w)));
    }
    *reinterpret_cast<short8*>(&Wl[pl][row * 64 + ((ch ^ (row & 7)) << 3)]) = v;
  }
  // W21/W22 hi B-frags into 64 VGPRs
  short8 Bh[2][4][2];
#pragma unroll
  for (int mat = 0; mat < 2; ++mat) {
    const float* Wm = mat ? W22 : W21;
#pragma unroll
    for (int nt = 0; nt < 4; ++nt)
#pragma unroll
      for (int ks = 0; ks < 2; ++ks) {
        const float4* p = reinterpret_cast<const float4*>(Wm + (nt * 16 + r15) * 64 + ks * 32 + g * 8);
        float4 va = p[0], vb = p[1];
        short8 h;
        h[0] = (short)f2bf(va.x); h[1] = (short)f2bf(va.y);
        h[2] = (short)f2bf(va.z); h[3] = (short)f2bf(va.w);
        h[4] = (short)f2bf(vb.x); h[5] = (short)f2bf(vb.y);
        h[6] = (short)f2bf(vb.z); h[7] = (short)f2bf(vb.w);
        Bh[mat][nt][ks] = h;
      }
  }
  __syncthreads();

  const int b0w = blockIdx.x * 16 + wv * 4;
  unsigned short* xw = &Xs[wv][0][0];
  float s1sum[4] = {0.f, 0.f, 0.f, 0.f};
  float c1f = 0.f;

  p1_step<4>(0, b0w, lane, g, r15, dsd1, dsd2, symp, dise, Wl[0], Wl[1], xw, Bh, s1sum, c1f);
  p1_step<4>(4, b0w, lane, g, r15, dsd1, dsd2, symp, dise, Wl[0], Wl[1], xw, Bh, s1sum, c1f);
  p1_step<2>(8, b0w, lane, g, r15, dsd1, dsd2, symp, dise, Wl[0], Wl[1], xw, Bh, s1sum, c1f);

  // c1f is uniform within each g-group; elem = b0w + g, cols d = nt*16 + r15
  float w1 = nb_w(c1f);
  float* dst = s1avg + (size_t)(b0w + g) * 64 + r15;
#pragma unroll
  for (int nt = 0; nt < 4; ++nt) dst[nt * 16] = s1sum[nt] * w1;
}

// ============ usu gather-average: quad-row loads (4 symp rows per instruction) ============
__global__ __launch_bounds__(256, 8) void hgnn_usu_avg(
    const int* __restrict__ usu1, const float* __restrict__ symp,
    float* __restrict__ mu) {
  const int tid = threadIdx.x;
  const int lane = tid & 63;
  const int wv = __builtin_amdgcn_readfirstlane(tid >> 6);
  const int grp = lane >> 4;
  const int d4 = (lane & 15) << 2;  // this lane's 4-dim slice
  const int b0 = blockIdx.x * 16 + wv * 4;

#pragma unroll
  for (int e = 0; e < 4; ++e) {
    const int b = b0 + e;
    int ui = 0;
    if (lane < MMN) ui = usu1[b * MMN + lane];
    float cnt = (float)__popcll(__ballot(ui != 0));
    f32x4 su = {0.f, 0.f, 0.f, 0.f};
    // 12 quad-iters cover m=0..47 (group grp takes m+grp); tail covers 48,49
#pragma unroll
    for (int m = 0; m < 48; m += 4) {
      int idx = __shfl(ui, m + grp, 64);
      su += *(const f32x4*)(symp + (idx << 6) + d4);  // symp row 0 is exactly zero
    }
    {
      int idx = __shfl(ui, 48 + grp, 64);
      if (grp < 2) su += *(const f32x4*)(symp + (idx << 6) + d4);
    }
#pragma unroll
    for (int c = 0; c < 4; ++c) {
      su[c] += __shfl_xor(su[c], 16, 64);
      su[c] += __shfl_xor(su[c], 32, 64);
    }
    float w = nb_w(cnt);
    if (lane < 16) {
      f32x4 r = su * w;
      *reinterpret_cast<f32x4*>(mu + (size_t)b * 64 + d4) = r;
    }
  }
}

// ================= final: label gather + 3 matvecs + dot (proven round-3 kernel) =================
__global__ __launch_bounds__(256, 2) void hgnn_final(
    const int* __restrict__ label, const float* __restrict__ dise,
    const float* __restrict__ W11, const float* __restrict__ W12,
    const float* __restrict__ Wu,
    const float* __restrict__ s1avg, const float* __restrict__ mu,
    float* __restrict__ out) {
  __shared__ float lw[3][4096];
  __shared__ float xb[4][4][3][64];
  const int tid = threadIdx.x;
  const int lane = tid & 63;
  const int wv = __builtin_amdgcn_readfirstlane(tid >> 6);
  stage_w(W11, lw[0], tid);
  stage_w(W12, lw[1], tid);
  stage_w(Wu, lw[2], tid);
  __syncthreads();

  const int b0 = blockIdx.x * 16 + wv * 4;
#pragma unroll
  for (int bi = 0; bi < 4; ++bi) {
    const int b = b0 + bi;
    float s1 = s1avg[(size_t)b * 64 + lane];
    float mv = mu[(size_t)b * 64 + lane];
    int lb = label[b];
    float t = dise[(lb << 6) | lane];
    xb[wv][bi][0][lane] = s1 + t;
    xb[wv][bi][1][lane] = s1 * t;
    xb[wv][bi][2][lane] = mv;
  }
  asm volatile("s_waitcnt lgkmcnt(0)" ::: "memory");

  float y1[4] = {0.f, 0.f, 0.f, 0.f};
  float y2[4] = {0.f, 0.f, 0.f, 0.f};
  const int swz = lane & 7;
#pragma unroll 4
  for (int q = 0; q < 16; ++q) {
    float4 wa = reinterpret_cast<float4*>(lw[0])[(lane << 4) | (q ^ swz)];
    float4 wb = reinterpret_cast<float4*>(lw[1])[(lane << 4) | (q ^ swz)];
    float4 wc = reinterpret_cast<float4*>(lw[2])[(lane << 4) | (q ^ swz)];
#pragma unroll
    for (int bi = 0; bi < 4; ++bi) {
      float4 xv1 = *reinterpret_cast<const float4*>(&xb[wv][bi][0][q << 2]);
      float4 xv2 = *reinterpret_cast<const float4*>(&xb[wv][bi][1][q << 2]);
      float4 xv3 = *reinterpret_cast<const float4*>(&xb[wv][bi][2][q << 2]);
      fma4(y1[bi], wa, xv1);
      fma4(y1[bi], wb, xv2);
      fma4(y2[bi], wc, xv3);
    }
  }
#pragma unroll
  for (int bi = 0; bi < 4; ++bi) {
    float ed = fast_tanh(y1[bi]);
    float eu = fast_tanh(y2[bi]);
    float p = ed * eu;
#pragma unroll
    for (int off = 32; off; off >>= 1) p += __shfl_xor(p, off, 64);
    if (lane == 0) out[b0 + bi] = p;
  }
}

extern "C" void kernel_launch(void* const* d_in, const int* in_sizes, int n_in,
                              void* d_out, int out_size, void* d_ws, size_t ws_size,
                              hipStream_t stream) {
  const int* dsd1 = (const int*)d_in[0];
  const int* dsd2 = (const int*)d_in[1];
  const int* usu1 = (const int*)d_in[2];
  const int* label = (const int*)d_in[3];
  const float* symp = (const float*)d_in[4];
  const float* dise = (const float*)d_in[5];
  const float* Wu = (const float*)d_in[6];
  const float* W21 = (const float*)d_in[7];
  const float* W22 = (const float*)d_in[8];
  const float* W11 = (const float*)d_in[9];
  const float* W12 = (const float*)d_in[10];
  float* out = (float*)d_out;

  const int B = in_sizes[3];
  float* s1 = (float*)d_ws;         // B*64 f32 = 4 MB
  float* mu = s1 + (size_t)B * 64;  // B*64 f32 = 4 MB

  hipLaunchKernelGGL(hgnn_phase1, dim3(B / 16), dim3(256), 0, stream,
                     dsd1, dsd2, symp, dise, W21, W22, s1);
  hipLaunchKernelGGL(hgnn_usu_avg, dim3(B / 16), dim3(256), 0, stream,
                     usu1, symp, mu);
  hipLaunchKernelGGL(hgnn_final, dim3(B / 16), dim3(256), 0, stream,
                     label, dise, W11, W12, Wu, s1, mu, out);
}

// Round 11
// 106.801 us; speedup vs baseline: 1.9831x; 1.0575x over previous
//
#include <hip/hip_runtime.h>

#define K1N 10
#define K2N 10
#define MMN 50

typedef __attribute__((ext_vector_type(8))) short short8;
typedef __attribute__((ext_vector_type(4))) float f32x4;

__device__ __forceinline__ float fast_tanh(float x) {
  x = fminf(fmaxf(x, -15.f), 15.f);
  float e2 = __expf(2.f * x);
  return (e2 - 1.f) * __builtin_amdgcn_rcpf(e2 + 1.f);
}

// reference's _avg_on_real_neighbor weight (exact f32 semantics)
__device__ __forceinline__ float nb_w(float cnt) {
  float w = 1.0f / (cnt + 1e-8f);
  return (w >= 1e8f) ? 0.f : w;
}

// f32 -> bf16 RNE as raw ushort; exact bf16 -> f32
__device__ __forceinline__ unsigned short f2bf(float x) {
  unsigned u = __builtin_bit_cast(unsigned, x);
  return (unsigned short)((u + 0x7FFFu + ((u >> 16) & 1u)) >> 16);
}
__device__ __forceinline__ float bf2f(unsigned short s) {
  return __builtin_bit_cast(float, ((unsigned)s) << 16);
}

__device__ __forceinline__ void fma4(float& y, float4 w, float4 x) {
  y = fmaf(w.x, x.x, y);
  y = fmaf(w.y, x.y, y);
  y = fmaf(w.z, x.z, y);
  y = fmaf(w.w, x.w, y);
}

// stage 64x64 f32 into LDS, XOR-swizzled float4 chunks (final kernel)
__device__ __forceinline__ void stage_w(const float* __restrict__ W, float* lds, int tid) {
  const float4* src = reinterpret_cast<const float4*>(W);
  float4* dst = reinterpret_cast<float4*>(lds);
#pragma unroll
  for (int i = 0; i < 4; ++i) {
    int c = tid + i * 256;
    int e = c >> 4, q = c & 15;
    dst[(e << 4) | (q ^ (e & 7))] = src[c];
  }
}

#define MFMA16(A, B, C) __builtin_amdgcn_mfma_f32_16x16x32_bf16(A, B, C, 0, 0, 0)

// one phase-1 k-chunk (round-7 proven dataflow): 16 MFMA rows, row u = bi*4+kq.
// Wave-wide coalesced gathers (lane = dim), X via per-wave swizzled LDS planes.
template <int KQ>
__device__ __forceinline__ void p1_step(
    int kbase, int b0w, int lane, int g, int r15,
    const int* __restrict__ dsd1, const int* __restrict__ dsd2,
    const float* __restrict__ symp, const float* __restrict__ dise,
    const unsigned short* __restrict__ Wl0, const unsigned short* __restrict__ Wl1,
    unsigned short* xw, const short8 (&Bh)[2][4][2],
    float (&s1sum)[4], float& c1f) {
  // ---- gather + 4-plane X writes (single pass) ----
#pragma unroll
  for (int u = 0; u < 16; ++u) {
    if ((u & 3) >= KQ) continue;
    const int b = b0w + (u >> 2);
    const int k = kbase + (u & 3);
    const int sidx = dsd1[b * K1N + k];         // wave-uniform -> s_load
    float es = symp[(sidx << 6) | lane];        // coalesced full row
    const int* dp = dsd2 + (b * K1N + k) * K2N; // wave-uniform -> s_load
    float acc = 0.f;
    int c2 = 0;
#pragma unroll
    for (int j = 0; j < K2N; ++j) {
      int dj = dp[j];
      c2 += (dj != 0);
      acc += dise[(dj << 6) | lane];            // dise row 0 is exactly zero
    }
    float w2 = (c2 == 0) ? 0.f : __builtin_amdgcn_rcpf((float)c2 + 1e-8f);
    float ad = acc * w2;
    float t1 = es + ad, t2 = es * ad;
    c1f += ((g == (u >> 2)) && (sidx != 0)) ? 1.f : 0.f;
    const int off = u * 64 + (((lane >> 3) ^ (u & 7)) << 3) + (lane & 7);
    unsigned short hh;
    hh = f2bf(t1); xw[off] = hh; xw[1024 + off] = f2bf(t1 - bf2f(hh));
    hh = f2bf(t2); xw[2048 + off] = hh; xw[3072 + off] = f2bf(t2 - bf2f(hh));
  }
  asm volatile("s_waitcnt lgkmcnt(0)" ::: "memory");  // own-wave X writes visible

  // ---- MFMA: Y = X1*W21^T + X2*W22^T, 3-term bf16 split; hi from regs, lo from LDS ----
  f32x4 acc4[4];
#pragma unroll
  for (int nt = 0; nt < 4; ++nt) acc4[nt] = (f32x4){0.f, 0.f, 0.f, 0.f};
#pragma unroll
  for (int ks = 0; ks < 2; ++ks) {
    const int aoff = r15 * 64 + (((4 * ks + g) ^ (r15 & 7)) << 3);
    short8 a1h = *(const short8*)(xw + aoff);
    short8 a1l = *(const short8*)(xw + 1024 + aoff);
    short8 a2h = *(const short8*)(xw + 2048 + aoff);
    short8 a2l = *(const short8*)(xw + 3072 + aoff);
#pragma unroll
    for (int nt = 0; nt < 4; ++nt) {
      const int wb = (nt * 16 + r15) * 64 + (((4 * ks + g) ^ (r15 & 7)) << 3);
      short8 w21l = *(const short8*)(Wl0 + wb);
      short8 w22l = *(const short8*)(Wl1 + wb);
      acc4[nt] = MFMA16(a1h, Bh[0][nt][ks], acc4[nt]);
      acc4[nt] = MFMA16(a1l, Bh[0][nt][ks], acc4[nt]);
      acc4[nt] = MFMA16(a1h, w21l, acc4[nt]);
      acc4[nt] = MFMA16(a2h, Bh[1][nt][ks], acc4[nt]);
      acc4[nt] = MFMA16(a2l, Bh[1][nt][ks], acc4[nt]);
      acc4[nt] = MFMA16(a2h, w22l, acc4[nt]);
    }
  }
  // ---- epilogue: rows 4g+rr belong to elem g (kq=rr); tanh + l2norm ----
#pragma unroll
  for (int rr = 0; rr < KQ; ++rr) {
    float ta[4], ss = 0.f;
#pragma unroll
    for (int nt = 0; nt < 4; ++nt) {
      ta[nt] = fast_tanh(acc4[nt][rr]);
      ss = fmaf(ta[nt], ta[nt], ss);
    }
    ss += __shfl_xor(ss, 1, 64); ss += __shfl_xor(ss, 2, 64);
    ss += __shfl_xor(ss, 4, 64); ss += __shfl_xor(ss, 8, 64);
    float inv = __builtin_amdgcn_rcpf(fmaxf(sqrtf(ss), 1e-12f));
#pragma unroll
    for (int nt = 0; nt < 4; ++nt) s1sum[nt] = fmaf(ta[nt], inv, s1sum[nt]);
  }
}

// ============ phase 1 + usu coda: 8 waves/block (512 thr), wave = 4 elems, 80 KB LDS ============
// 2 blocks/CU x 8 waves = 16 waves/CU (vs 12 at 256-thr/48KB); grid 512 = exactly 2/CU.
// usu gather runs as a streaming coda after the k-loop -> overlaps other blocks' latency.
__global__ __launch_bounds__(512, 2) void hgnn_phase1(
    const int* __restrict__ dsd1, const int* __restrict__ dsd2,
    const int* __restrict__ usu1,
    const float* __restrict__ symp, const float* __restrict__ dise,
    const float* __restrict__ W21, const float* __restrict__ W22,
    float* __restrict__ s1avg, float* __restrict__ mu) {
  __shared__ unsigned short Wl[2][4096];     // {w21lo, w22lo} swizzled bf16 planes (16 KB)
  __shared__ unsigned short Xs[8][4][1024];  // per-wave {t1h,t1l,t2h,t2l} (64 KB)
  const int tid = threadIdx.x;
  const int lane = tid & 63;
  const int wv = __builtin_amdgcn_readfirstlane(tid >> 6);
  const int g = lane >> 4, r15 = lane & 15;

  // stage W lo planes: 1024 16B-chunks, 2/thread
#pragma unroll
  for (int i = 0; i < 2; ++i) {
    int c = tid + (i << 9);
    int pl = c >> 9, rc = c & 511;
    int row = rc >> 3, ch = rc & 7;
    const float* src = (pl ? W22 : W21) + row * 64 + ch * 8;
    short8 v;
#pragma unroll
    for (int j = 0; j < 8; ++j) {
      float w = src[j];
      v[j] = (short)f2bf(w - bf2f(f2bf(w)));
    }
    *reinterpret_cast<short8*>(&Wl[pl][row * 64 + ((ch ^ (row & 7)) << 3)]) = v;
  }
  // W21/W22 hi B-frags into 64 VGPRs
  short8 Bh[2][4][2];
#pragma unroll
  for (int mat = 0; mat < 2; ++mat) {
    const float* Wm = mat ? W22 : W21;
#pragma unroll
    for (int nt = 0; nt < 4; ++nt)
#pragma unroll
      for (int ks = 0; ks < 2; ++ks) {
        const float4* p = reinterpret_cast<const float4*>(Wm + (nt * 16 + r15) * 64 + ks * 32 + g * 8);
        float4 va = p[0], vb = p[1];
        short8 h;
        h[0] = (short)f2bf(va.x); h[1] = (short)f2bf(va.y);
        h[2] = (short)f2bf(va.z); h[3] = (short)f2bf(va.w);
        h[4] = (short)f2bf(vb.x); h[5] = (short)f2bf(vb.y);
        h[6] = (short)f2bf(vb.z); h[7] = (short)f2bf(vb.w);
        Bh[mat][nt][ks] = h;
      }
  }
  __syncthreads();

  const int b0w = blockIdx.x * 32 + wv * 4;
  unsigned short* xw = &Xs[wv][0][0];
  float s1sum[4] = {0.f, 0.f, 0.f, 0.f};
  float c1f = 0.f;

  p1_step<4>(0, b0w, lane, g, r15, dsd1, dsd2, symp, dise, Wl[0], Wl[1], xw, Bh, s1sum, c1f);
  p1_step<4>(4, b0w, lane, g, r15, dsd1, dsd2, symp, dise, Wl[0], Wl[1], xw, Bh, s1sum, c1f);
  p1_step<2>(8, b0w, lane, g, r15, dsd1, dsd2, symp, dise, Wl[0], Wl[1], xw, Bh, s1sum, c1f);

  // c1f is uniform within each g-group; elem = b0w + g, cols d = nt*16 + r15
  float w1 = nb_w(c1f);
  float* dst = s1avg + (size_t)(b0w + g) * 64 + r15;
#pragma unroll
  for (int nt = 0; nt < 4; ++nt) dst[nt * 16] = s1sum[nt] * w1;

  // ---- usu coda: quad-row gather-average for this wave's 4 elems (no barriers) ----
  const int grp = lane >> 4;
  const int d4 = (lane & 15) << 2;
#pragma unroll
  for (int e = 0; e < 4; ++e) {
    const int b = b0w + e;
    int ui = 0;
    if (lane < MMN) ui = usu1[b * MMN + lane];
    float cnt = (float)__popcll(__ballot(ui != 0));
    f32x4 su = {0.f, 0.f, 0.f, 0.f};
#pragma unroll
    for (int m = 0; m < 48; m += 4) {
      int idx = __shfl(ui, m + grp, 64);
      su += *(const f32x4*)(symp + (idx << 6) + d4);  // symp row 0 is exactly zero
    }
    {
      int idx = __shfl(ui, 48 + grp, 64);
      if (grp < 2) su += *(const f32x4*)(symp + (idx << 6) + d4);
    }
#pragma unroll
    for (int c = 0; c < 4; ++c) {
      su[c] += __shfl_xor(su[c], 16, 64);
      su[c] += __shfl_xor(su[c], 32, 64);
    }
    float w = nb_w(cnt);
    if (lane < 16) {
      f32x4 r = su * w;
      *reinterpret_cast<f32x4*>(mu + (size_t)b * 64 + d4) = r;
    }
  }
}

// ================= final: label gather + 3 matvecs + dot (proven round-3 kernel) =================
__global__ __launch_bounds__(256, 2) void hgnn_final(
    const int* __restrict__ label, const float* __restrict__ dise,
    const float* __restrict__ W11, const float* __restrict__ W12,
    const float* __restrict__ Wu,
    const float* __restrict__ s1avg, const float* __restrict__ mu,
    float* __restrict__ out) {
  __shared__ float lw[3][4096];
  __shared__ float xb[4][4][3][64];
  const int tid = threadIdx.x;
  const int lane = tid & 63;
  const int wv = __builtin_amdgcn_readfirstlane(tid >> 6);
  stage_w(W11, lw[0], tid);
  stage_w(W12, lw[1], tid);
  stage_w(Wu, lw[2], tid);
  __syncthreads();

  const int b0 = blockIdx.x * 16 + wv * 4;
#pragma unroll
  for (int bi = 0; bi < 4; ++bi) {
    const int b = b0 + bi;
    float s1 = s1avg[(size_t)b * 64 + lane];
    float mv = mu[(size_t)b * 64 + lane];
    int lb = label[b];
    float t = dise[(lb << 6) | lane];
    xb[wv][bi][0][lane] = s1 + t;
    xb[wv][bi][1][lane] = s1 * t;
    xb[wv][bi][2][lane] = mv;
  }
  asm volatile("s_waitcnt lgkmcnt(0)" ::: "memory");

  float y1[4] = {0.f, 0.f, 0.f, 0.f};
  float y2[4] = {0.f, 0.f, 0.f, 0.f};
  const int swz = lane & 7;
#pragma unroll 4
  for (int q = 0; q < 16; ++q) {
    float4 wa = reinterpret_cast<float4*>(lw[0])[(lane << 4) | (q ^ swz)];
    float4 wb = reinterpret_cast<float4*>(lw[1])[(lane << 4) | (q ^ swz)];
    float4 wc = reinterpret_cast<float4*>(lw[2])[(lane << 4) | (q ^ swz)];
#pragma unroll
    for (int bi = 0; bi < 4; ++bi) {
      float4 xv1 = *reinterpret_cast<const float4*>(&xb[wv][bi][0][q << 2]);
      float4 xv2 = *reinterpret_cast<const float4*>(&xb[wv][bi][1][q << 2]);
      float4 xv3 = *reinterpret_cast<const float4*>(&xb[wv][bi][2][q << 2]);
      fma4(y1[bi], wa, xv1);
      fma4(y1[bi], wb, xv2);
      fma4(y2[bi], wc, xv3);
    }
  }
#pragma unroll
  for (int bi = 0; bi < 4; ++bi) {
    float ed = fast_tanh(y1[bi]);
    float eu = fast_tanh(y2[bi]);
    float p = ed * eu;
#pragma unroll
    for (int off = 32; off; off >>= 1) p += __shfl_xor(p, off, 64);
    if (lane == 0) out[b0 + bi] = p;
  }
}

extern "C" void kernel_launch(void* const* d_in, const int* in_sizes, int n_in,
                              void* d_out, int out_size, void* d_ws, size_t ws_size,
                              hipStream_t stream) {
  const int* dsd1 = (const int*)d_in[0];
  const int* dsd2 = (const int*)d_in[1];
  const int* usu1 = (const int*)d_in[2];
  const int* label = (const int*)d_in[3];
  const float* symp = (const float*)d_in[4];
  const float* dise = (const float*)d_in[5];
  const float* Wu = (const float*)d_in[6];
  const float* W21 = (const float*)d_in[7];
  const float* W22 = (const float*)d_in[8];
  const float* W11 = (const float*)d_in[9];
  const float* W12 = (const float*)d_in[10];
  float* out = (float*)d_out;

  const int B = in_sizes[3];
  float* s1 = (float*)d_ws;         // B*64 f32 = 4 MB
  float* mu = s1 + (size_t)B * 64;  // B*64 f32 = 4 MB

  hipLaunchKernelGGL(hgnn_phase1, dim3(B / 32), dim3(512), 0, stream,
                     dsd1, dsd2, usu1, symp, dise, W21, W22, s1, mu);
  hipLaunchKernelGGL(hgnn_final, dim3(B / 16), dim3(256), 0, stream,
                     label, dise, W11, W12, Wu, s1, mu, out);
}

// Round 13
// 89.737 us; speedup vs baseline: 2.3602x; 1.1902x over previous
//
#include <hip/hip_runtime.h>

#define K1N 10
#define K2N 10
#define MMN 50

typedef __attribute__((ext_vector_type(8))) short short8;
typedef __attribute__((ext_vector_type(4))) float f32x4;
typedef __attribute__((ext_vector_type(4))) unsigned short us16x4;

__device__ __forceinline__ float fast_tanh(float x) {
  x = fminf(fmaxf(x, -15.f), 15.f);
  float e2 = __expf(2.f * x);
  return (e2 - 1.f) * __builtin_amdgcn_rcpf(e2 + 1.f);
}

// reference's _avg_on_real_neighbor weight (exact f32 semantics)
__device__ __forceinline__ float nb_w(float cnt) {
  float w = 1.0f / (cnt + 1e-8f);
  return (w >= 1e8f) ? 0.f : w;
}

// f32 -> bf16 RNE as raw ushort; exact bf16 -> f32
__device__ __forceinline__ unsigned short f2bf(float x) {
  unsigned u = __builtin_bit_cast(unsigned, x);
  return (unsigned short)((u + 0x7FFFu + ((u >> 16) & 1u)) >> 16);
}
__device__ __forceinline__ float bf2f(unsigned short s) {
  return __builtin_bit_cast(float, ((unsigned)s) << 16);
}

__device__ __forceinline__ void fma4(float& y, float4 w, float4 x) {
  y = fmaf(w.x, x.x, y);
  y = fmaf(w.y, x.y, y);
  y = fmaf(w.z, x.z, y);
  y = fmaf(w.w, x.w, y);
}

// stage 64x64 f32 into LDS, XOR-swizzled float4 chunks (final kernel)
__device__ __forceinline__ void stage_w(const float* __restrict__ W, float* lds, int tid) {
  const float4* src = reinterpret_cast<const float4*>(W);
  float4* dst = reinterpret_cast<float4*>(lds);
#pragma unroll
  for (int i = 0; i < 4; ++i) {
    int c = tid + i * 256;
    int e = c >> 4, q = c & 15;
    dst[(e << 4) | (q ^ (e & 7))] = src[c];
  }
}

#define MFMA16(A, B, C) __builtin_amdgcn_mfma_f32_16x16x32_bf16(A, B, C, 0, 0, 0)

// one phase-1 k-chunk, QUAD-ROW gather version.
// Lane group grp=lane>>4 owns elem b0w+grp; 16 lanes (c16) x f32x4 = one full 256B row.
// One load instruction fetches 4 elems' rows (1KB, full lines). Row u = grp*4+kq.
template <int KQ>
__device__ __forceinline__ void p1_step(
    int kbase, int b0w, int lane, int grp, int c16, int r15, int g, int bpi,
    const int* __restrict__ dsd2,
    const float* __restrict__ symp, const float* __restrict__ dise,
    int sd /* preloaded dsd1: lane c16<10 holds k=c16 of elem grp */,
    const unsigned short* __restrict__ Wl0, const unsigned short* __restrict__ Wl1,
    unsigned short* xw, const short8 (&Bh)[2][4][2],
    float (&s1sum)[4]) {
  // ---- vector preload of this step's dsd2 indices (KQ*10 ints per elem, contiguous) ----
  int4 i4 = {0, 0, 0, 0};
  const int lim = (KQ * 10 + 3) >> 2;  // 10 (KQ=4) or 5 (KQ=2): avoids OOB on last elem
  if (c16 < lim)
    i4 = *reinterpret_cast<const int4*>(dsd2 + (b0w + grp) * (K1N * K2N) + kbase * K2N + (c16 << 2));
  int idxa[4] = {i4.x, i4.y, i4.z, i4.w};

  // ---- gather: per kq, 1 symp quad + 10 dise quads; acc in f32x4 (dims c16*4..+4) ----
  f32x4 acc[KQ], esv[KQ];
  int c2[KQ];
  int sxv[KQ];
#pragma unroll
  for (int kq = 0; kq < KQ; ++kq) {
    acc[kq] = (f32x4){0.f, 0.f, 0.f, 0.f};
    c2[kq] = 0;
    sxv[kq] = __builtin_amdgcn_ds_bpermute(bpi + ((kbase + kq) << 2), sd);
  }
#pragma unroll
  for (int kq = 0; kq < KQ; ++kq)
    esv[kq] = *reinterpret_cast<const f32x4*>(symp + (sxv[kq] << 6) + (c16 << 2));
#pragma unroll
  for (int m = 0; m < K2N; ++m) {
#pragma unroll
    for (int kq = 0; kq < KQ; ++kq) {
      const int f = kq * K2N + m;
      int idxv = __builtin_amdgcn_ds_bpermute(bpi + ((f >> 2) << 2), idxa[f & 3]);
      c2[kq] += (idxv != 0);
      acc[kq] += *reinterpret_cast<const f32x4*>(dise + (idxv << 6) + (c16 << 2));  // row 0 = 0
    }
  }

  // ---- t1/t2, bf16 split, swizzled LDS writes (8B per lane per plane) ----
#pragma unroll
  for (int kq = 0; kq < KQ; ++kq) {
    float w2 = (c2[kq] == 0) ? 0.f : __builtin_amdgcn_rcpf((float)c2[kq] + 1e-8f);
    f32x4 ad = acc[kq] * w2;
    f32x4 t1 = esv[kq] + ad;
    f32x4 t2 = esv[kq] * ad;
    const int u = (grp << 2) | kq;
    const int off = u * 64 + (((c16 >> 1) ^ (u & 7)) << 3) + ((c16 & 1) << 2);
    us16x4 h1, l1, h2, l2;
#pragma unroll
    for (int c = 0; c < 4; ++c) {
      unsigned short hh = f2bf(t1[c]);
      h1[c] = hh;
      l1[c] = f2bf(t1[c] - bf2f(hh));
      unsigned short h2c = f2bf(t2[c]);
      h2[c] = h2c;
      l2[c] = f2bf(t2[c] - bf2f(h2c));
    }
    *reinterpret_cast<us16x4*>(xw + off) = h1;
    *reinterpret_cast<us16x4*>(xw + 1024 + off) = l1;
    *reinterpret_cast<us16x4*>(xw + 2048 + off) = h2;
    *reinterpret_cast<us16x4*>(xw + 3072 + off) = l2;
  }
  asm volatile("s_waitcnt lgkmcnt(0)" ::: "memory");  // own-wave X writes visible

  // ---- MFMA: Y = X1*W21^T + X2*W22^T, 3-term bf16 split; hi from regs, lo from LDS ----
  f32x4 acc4[4];
#pragma unroll
  for (int nt = 0; nt < 4; ++nt) acc4[nt] = (f32x4){0.f, 0.f, 0.f, 0.f};
#pragma unroll
  for (int ks = 0; ks < 2; ++ks) {
    const int aoff = r15 * 64 + (((4 * ks + g) ^ (r15 & 7)) << 3);
    short8 a1h = *(const short8*)(xw + aoff);
    short8 a1l = *(const short8*)(xw + 1024 + aoff);
    short8 a2h = *(const short8*)(xw + 2048 + aoff);
    short8 a2l = *(const short8*)(xw + 3072 + aoff);
#pragma unroll
    for (int nt = 0; nt < 4; ++nt) {
      const int wb = (nt * 16 + r15) * 64 + (((4 * ks + g) ^ (r15 & 7)) << 3);
      short8 w21l = *(const short8*)(Wl0 + wb);
      short8 w22l = *(const short8*)(Wl1 + wb);
      acc4[nt] = MFMA16(a1h, Bh[0][nt][ks], acc4[nt]);
      acc4[nt] = MFMA16(a1l, Bh[0][nt][ks], acc4[nt]);
      acc4[nt] = MFMA16(a1h, w21l, acc4[nt]);
      acc4[nt] = MFMA16(a2h, Bh[1][nt][ks], acc4[nt]);
      acc4[nt] = MFMA16(a2l, Bh[1][nt][ks], acc4[nt]);
      acc4[nt] = MFMA16(a2h, w22l, acc4[nt]);
    }
  }
  // ---- epilogue: rows 4g+rr belong to elem g (kq=rr); tanh + l2norm ----
#pragma unroll
  for (int rr = 0; rr < KQ; ++rr) {
    float ta[4], ss = 0.f;
#pragma unroll
    for (int nt = 0; nt < 4; ++nt) {
      ta[nt] = fast_tanh(acc4[nt][rr]);
      ss = fmaf(ta[nt], ta[nt], ss);
    }
    ss += __shfl_xor(ss, 1, 64); ss += __shfl_xor(ss, 2, 64);
    ss += __shfl_xor(ss, 4, 64); ss += __shfl_xor(ss, 8, 64);
    float inv = __builtin_amdgcn_rcpf(fmaxf(sqrtf(ss), 1e-12f));
#pragma unroll
    for (int nt = 0; nt < 4; ++nt) s1sum[nt] = fmaf(ta[nt], inv, s1sum[nt]);
  }
}

// ============ phase 1 + usu coda: 8 waves/block (512 thr), wave = 4 elems, 80 KB LDS ============
__global__ __launch_bounds__(512, 2) void hgnn_phase1(
    const int* __restrict__ dsd1, const int* __restrict__ dsd2,
    const int* __restrict__ usu1,
    const float* __restrict__ symp, const float* __restrict__ dise,
    const float* __restrict__ W21, const float* __restrict__ W22,
    float* __restrict__ s1avg, float* __restrict__ mu) {
  __shared__ unsigned short Wl[2][4096];     // {w21lo, w22lo} swizzled bf16 planes (16 KB)
  __shared__ unsigned short Xs[8][4][1024];  // per-wave {t1h,t1l,t2h,t2l} (64 KB)
  const int tid = threadIdx.x;
  const int lane = tid & 63;
  const int wv = __builtin_amdgcn_readfirstlane(tid >> 6);
  const int g = lane >> 4, r15 = lane & 15;
  const int grp = g, c16 = r15;
  const int bpi = (lane & 48) << 2;  // bpermute byte-base of this lane's group

  // stage W lo planes: 1024 16B-chunks, 2/thread
#pragma unroll
  for (int i = 0; i < 2; ++i) {
    int c = tid + (i << 9);
    int pl = c >> 9, rc = c & 511;
    int row = rc >> 3, ch = rc & 7;
    const float* src = (pl ? W22 : W21) + row * 64 + ch * 8;
    short8 v;
#pragma unroll
    for (int j = 0; j < 8; ++j) {
      float w = src[j];
      v[j] = (short)f2bf(w - bf2f(f2bf(w)));
    }
    *reinterpret_cast<short8*>(&Wl[pl][row * 64 + ((ch ^ (row & 7)) << 3)]) = v;
  }
  // W21/W22 hi B-frags into 64 VGPRs
  short8 Bh[2][4][2];
#pragma unroll
  for (int mat = 0; mat < 2; ++mat) {
    const float* Wm = mat ? W22 : W21;
#pragma unroll
    for (int nt = 0; nt < 4; ++nt)
#pragma unroll
      for (int ks = 0; ks < 2; ++ks) {
        const float4* p = reinterpret_cast<const float4*>(Wm + (nt * 16 + r15) * 64 + ks * 32 + g * 8);
        float4 va = p[0], vb = p[1];
        short8 h;
        h[0] = (short)f2bf(va.x); h[1] = (short)f2bf(va.y);
        h[2] = (short)f2bf(va.z); h[3] = (short)f2bf(va.w);
        h[4] = (short)f2bf(vb.x); h[5] = (short)f2bf(vb.y);
        h[6] = (short)f2bf(vb.z); h[7] = (short)f2bf(vb.w);
        Bh[mat][nt][ks] = h;
      }
  }
  __syncthreads();

  const int b0w = blockIdx.x * 32 + wv * 4;
  unsigned short* xw = &Xs[wv][0][0];
  float s1sum[4] = {0.f, 0.f, 0.f, 0.f};

  // preload dsd1 for this wave's 4 elems: lane c16<10 holds k=c16 of elem grp
  int sd = 0;
  if (c16 < K1N) sd = dsd1[(b0w + grp) * K1N + c16];
  // c1 per elem via one ballot (bits [grp*16, grp*16+10))
  unsigned long long ball = __ballot((c16 < K1N) && (sd != 0));
  float c1f = (float)__popcll(ball & (1023ull << (grp << 4)));

  p1_step<4>(0, b0w, lane, grp, c16, r15, g, bpi, dsd2, symp, dise, sd, Wl[0], Wl[1], xw, Bh, s1sum);
  p1_step<4>(4, b0w, lane, grp, c16, r15, g, bpi, dsd2, symp, dise, sd, Wl[0], Wl[1], xw, Bh, s1sum);
  p1_step<2>(8, b0w, lane, grp, c16, r15, g, bpi, dsd2, symp, dise, sd, Wl[0], Wl[1], xw, Bh, s1sum);

  // elem = b0w + g, cols d = nt*16 + r15
  float w1 = nb_w(c1f);
  float* dst = s1avg + (size_t)(b0w + g) * 64 + r15;
#pragma unroll
  for (int nt = 0; nt < 4; ++nt) dst[nt * 16] = s1sum[nt] * w1;

  // ---- usu coda: quad-row gather-average for this wave's 4 elems (no barriers) ----
  const int d4 = (lane & 15) << 2;
#pragma unroll
  for (int e = 0; e < 4; ++e) {
    const int b = b0w + e;
    int ui = 0;
    if (lane < MMN) ui = usu1[b * MMN + lane];
    float cnt = (float)__popcll(__ballot(ui != 0));
    f32x4 su = {0.f, 0.f, 0.f, 0.f};
#pragma unroll
    for (int m = 0; m < 48; m += 4) {
      int idx = __shfl(ui, m + grp, 64);
      su += *(const f32x4*)(symp + (idx << 6) + d4);  // symp row 0 is exactly zero
    }
    {
      int idx = __shfl(ui, 48 + grp, 64);
      if (grp < 2) su += *(const f32x4*)(symp + (idx << 6) + d4);
    }
#pragma unroll
    for (int c = 0; c < 4; ++c) {
      su[c] += __shfl_xor(su[c], 16, 64);
      su[c] += __shfl_xor(su[c], 32, 64);
    }
    float w = nb_w(cnt);
    if (lane < 16) {
      f32x4 r = su * w;
      *reinterpret_cast<f32x4*>(mu + (size_t)b * 64 + d4) = r;
    }
  }
}

// ================= final: label gather + 3 matvecs + dot (proven round-3 kernel) =================
__global__ __launch_bounds__(256, 2) void hgnn_final(
    const int* __restrict__ label, const float* __restrict__ dise,
    const float* __restrict__ W11, const float* __restrict__ W12,
    const float* __restrict__ Wu,
    const float* __restrict__ s1avg, const float* __restrict__ mu,
    float* __restrict__ out) {
  __shared__ float lw[3][4096];
  __shared__ float xb[4][4][3][64];
  const int tid = threadIdx.x;
  const int lane = tid & 63;
  const int wv = __builtin_amdgcn_readfirstlane(tid >> 6);
  stage_w(W11, lw[0], tid);
  stage_w(W12, lw[1], tid);
  stage_w(Wu, lw[2], tid);
  __syncthreads();

  const int b0 = blockIdx.x * 16 + wv * 4;
#pragma unroll
  for (int bi = 0; bi < 4; ++bi) {
    const int b = b0 + bi;
    float s1 = s1avg[(size_t)b * 64 + lane];
    float mv = mu[(size_t)b * 64 + lane];
    int lb = label[b];
    float t = dise[(lb << 6) | lane];
    xb[wv][bi][0][lane] = s1 + t;
    xb[wv][bi][1][lane] = s1 * t;
    xb[wv][bi][2][lane] = mv;
  }
  asm volatile("s_waitcnt lgkmcnt(0)" ::: "memory");

  float y1[4] = {0.f, 0.f, 0.f, 0.f};
  float y2[4] = {0.f, 0.f, 0.f, 0.f};
  const int swz = lane & 7;
#pragma unroll 4
  for (int q = 0; q < 16; ++q) {
    float4 wa = reinterpret_cast<float4*>(lw[0])[(lane << 4) | (q ^ swz)];
    float4 wb = reinterpret_cast<float4*>(lw[1])[(lane << 4) | (q ^ swz)];
    float4 wc = reinterpret_cast<float4*>(lw[2])[(lane << 4) | (q ^ swz)];
#pragma unroll
    for (int bi = 0; bi < 4; ++bi) {
      float4 xv1 = *reinterpret_cast<const float4*>(&xb[wv][bi][0][q << 2]);
      float4 xv2 = *reinterpret_cast<const float4*>(&xb[wv][bi][1][q << 2]);
      float4 xv3 = *reinterpret_cast<const float4*>(&xb[wv][bi][2][q << 2]);
      fma4(y1[bi], wa, xv1);
      fma4(y1[bi], wb, xv2);
      fma4(y2[bi], wc, xv3);
    }
  }
#pragma unroll
  for (int bi = 0; bi < 4; ++bi) {
    float ed = fast_tanh(y1[bi]);
    float eu = fast_tanh(y2[bi]);
    float p = ed * eu;
#pragma unroll
    for (int off = 32; off; off >>= 1) p += __shfl_xor(p, off, 64);
    if (lane == 0) out[b0 + bi] = p;
  }
}

extern "C" void kernel_launch(void* const* d_in, const int* in_sizes, int n_in,
                              void* d_out, int out_size, void* d_ws, size_t ws_size,
                              hipStream_t stream) {
  const int* dsd1 = (const int*)d_in[0];
  const int* dsd2 = (const int*)d_in[1];
  const int* usu1 = (const int*)d_in[2];
  const int* label = (const int*)d_in[3];
  const float* symp = (const float*)d_in[4];
  const float* dise = (const float*)d_in[5];
  const float* Wu = (const float*)d_in[6];
  const float* W21 = (const float*)d_in[7];
  const float* W22 = (const float*)d_in[8];
  const float* W11 = (const float*)d_in[9];
  const float* W12 = (const float*)d_in[10];
  float* out = (float*)d_out;

  const int B = in_sizes[3];
  float* s1 = (float*)d_ws;         // B*64 f32 = 4 MB
  float* mu = s1 + (size_t)B * 64;  // B*64 f32 = 4 MB

  hipLaunchKernelGGL(hgnn_phase1, dim3(B / 32), dim3(512), 0, stream,
                     dsd1, dsd2, usu1, symp, dise, W21, W22, s1, mu);
  hipLaunchKernelGGL(hgnn_final, dim3(B / 16), dim3(256), 0, stream,
                     label, dise, W11, W12, Wu, s1, mu, out);
}

// Round 14
// 87.367 us; speedup vs baseline: 2.4243x; 1.0271x over previous
//
#include <hip/hip_runtime.h>

#define K1N 10
#define K2N 10
#define MMN 50

typedef __attribute__((ext_vector_type(8))) short short8;
typedef __attribute__((ext_vector_type(4))) float f32x4;
typedef __attribute__((ext_vector_type(4))) unsigned short us16x4;

__device__ __forceinline__ float fast_tanh(float x) {
  x = fminf(fmaxf(x, -15.f), 15.f);
  float e2 = __expf(2.f * x);
  return (e2 - 1.f) * __builtin_amdgcn_rcpf(e2 + 1.f);
}

// reference's _avg_on_real_neighbor weight (exact f32 semantics)
__device__ __forceinline__ float nb_w(float cnt) {
  float w = 1.0f / (cnt + 1e-8f);
  return (w >= 1e8f) ? 0.f : w;
}

// f32 -> bf16 RNE as raw ushort; exact bf16 -> f32
__device__ __forceinline__ unsigned short f2bf(float x) {
  unsigned u = __builtin_bit_cast(unsigned, x);
  return (unsigned short)((u + 0x7FFFu + ((u >> 16) & 1u)) >> 16);
}
__device__ __forceinline__ float bf2f(unsigned short s) {
  return __builtin_bit_cast(float, ((unsigned)s) << 16);
}

__device__ __forceinline__ void fma4(float& y, float4 w, float4 x) {
  y = fmaf(w.x, x.x, y);
  y = fmaf(w.y, x.y, y);
  y = fmaf(w.z, x.z, y);
  y = fmaf(w.w, x.w, y);
}

#define MFMA16(A, B, C) __builtin_amdgcn_mfma_f32_16x16x32_bf16(A, B, C, 0, 0, 0)

// one phase-1 k-chunk, QUAD-ROW gather (round-13 proven).
// Lane group grp=lane>>4 owns elem b0w+grp; 16 lanes (c16) x f32x4 = one full 256B row.
template <int KQ>
__device__ __forceinline__ void p1_step(
    int kbase, int b0w, int lane, int grp, int c16, int r15, int g, int bpi,
    const int* __restrict__ dsd2,
    const float* __restrict__ symp, const float* __restrict__ dise,
    int sd, const unsigned short* __restrict__ Wl0, const unsigned short* __restrict__ Wl1,
    unsigned short* xw, const short8 (&Bh)[2][4][2],
    float (&s1sum)[4]) {
  int4 i4 = {0, 0, 0, 0};
  const int lim = (KQ * 10 + 3) >> 2;
  if (c16 < lim)
    i4 = *reinterpret_cast<const int4*>(dsd2 + (b0w + grp) * (K1N * K2N) + kbase * K2N + (c16 << 2));
  int idxa[4] = {i4.x, i4.y, i4.z, i4.w};

  f32x4 acc[KQ], esv[KQ];
  int c2[KQ];
  int sxv[KQ];
#pragma unroll
  for (int kq = 0; kq < KQ; ++kq) {
    acc[kq] = (f32x4){0.f, 0.f, 0.f, 0.f};
    c2[kq] = 0;
    sxv[kq] = __builtin_amdgcn_ds_bpermute(bpi + ((kbase + kq) << 2), sd);
  }
#pragma unroll
  for (int kq = 0; kq < KQ; ++kq)
    esv[kq] = *reinterpret_cast<const f32x4*>(symp + (sxv[kq] << 6) + (c16 << 2));
#pragma unroll
  for (int m = 0; m < K2N; ++m) {
#pragma unroll
    for (int kq = 0; kq < KQ; ++kq) {
      const int f = kq * K2N + m;
      int idxv = __builtin_amdgcn_ds_bpermute(bpi + ((f >> 2) << 2), idxa[f & 3]);
      c2[kq] += (idxv != 0);
      acc[kq] += *reinterpret_cast<const f32x4*>(dise + (idxv << 6) + (c16 << 2));  // row 0 = 0
    }
  }

#pragma unroll
  for (int kq = 0; kq < KQ; ++kq) {
    float w2 = (c2[kq] == 0) ? 0.f : __builtin_amdgcn_rcpf((float)c2[kq] + 1e-8f);
    f32x4 ad = acc[kq] * w2;
    f32x4 t1 = esv[kq] + ad;
    f32x4 t2 = esv[kq] * ad;
    const int u = (grp << 2) | kq;
    const int off = u * 64 + (((c16 >> 1) ^ (u & 7)) << 3) + ((c16 & 1) << 2);
    us16x4 h1, l1, h2, l2;
#pragma unroll
    for (int c = 0; c < 4; ++c) {
      unsigned short hh = f2bf(t1[c]);
      h1[c] = hh;
      l1[c] = f2bf(t1[c] - bf2f(hh));
      unsigned short h2c = f2bf(t2[c]);
      h2[c] = h2c;
      l2[c] = f2bf(t2[c] - bf2f(h2c));
    }
    *reinterpret_cast<us16x4*>(xw + off) = h1;
    *reinterpret_cast<us16x4*>(xw + 1024 + off) = l1;
    *reinterpret_cast<us16x4*>(xw + 2048 + off) = h2;
    *reinterpret_cast<us16x4*>(xw + 3072 + off) = l2;
  }
  asm volatile("s_waitcnt lgkmcnt(0)" ::: "memory");

  f32x4 acc4[4];
#pragma unroll
  for (int nt = 0; nt < 4; ++nt) acc4[nt] = (f32x4){0.f, 0.f, 0.f, 0.f};
#pragma unroll
  for (int ks = 0; ks < 2; ++ks) {
    const int aoff = r15 * 64 + (((4 * ks + g) ^ (r15 & 7)) << 3);
    short8 a1h = *(const short8*)(xw + aoff);
    short8 a1l = *(const short8*)(xw + 1024 + aoff);
    short8 a2h = *(const short8*)(xw + 2048 + aoff);
    short8 a2l = *(const short8*)(xw + 3072 + aoff);
#pragma unroll
    for (int nt = 0; nt < 4; ++nt) {
      const int wb = (nt * 16 + r15) * 64 + (((4 * ks + g) ^ (r15 & 7)) << 3);
      short8 w21l = *(const short8*)(Wl0 + wb);
      short8 w22l = *(const short8*)(Wl1 + wb);
      acc4[nt] = MFMA16(a1h, Bh[0][nt][ks], acc4[nt]);
      acc4[nt] = MFMA16(a1l, Bh[0][nt][ks], acc4[nt]);
      acc4[nt] = MFMA16(a1h, w21l, acc4[nt]);
      acc4[nt] = MFMA16(a2h, Bh[1][nt][ks], acc4[nt]);
      acc4[nt] = MFMA16(a2l, Bh[1][nt][ks], acc4[nt]);
      acc4[nt] = MFMA16(a2h, w22l, acc4[nt]);
    }
  }
#pragma unroll
  for (int rr = 0; rr < KQ; ++rr) {
    float ta[4], ss = 0.f;
#pragma unroll
    for (int nt = 0; nt < 4; ++nt) {
      ta[nt] = fast_tanh(acc4[nt][rr]);
      ss = fmaf(ta[nt], ta[nt], ss);
    }
    ss += __shfl_xor(ss, 1, 64); ss += __shfl_xor(ss, 2, 64);
    ss += __shfl_xor(ss, 4, 64); ss += __shfl_xor(ss, 8, 64);
    float inv = __builtin_amdgcn_rcpf(fmaxf(sqrtf(ss), 1e-12f));
#pragma unroll
    for (int nt = 0; nt < 4; ++nt) s1sum[nt] = fmaf(ta[nt], inv, s1sum[nt]);
  }
}

// ====== FULLY FUSED: phase1 (MFMA) + usu coda + final matvec/dot, one kernel ======
// 8 waves/block (512 thr), wave = 4 elems, 80 KB LDS, 2 blocks/CU.
// LDS life: [k-loop: Wl 16K + Xs 64K] --sync--> [final: lw 48K f32-W + xb 24K]
__global__ __launch_bounds__(512, 2) void hgnn_fused(
    const int* __restrict__ dsd1, const int* __restrict__ dsd2,
    const int* __restrict__ usu1, const int* __restrict__ label,
    const float* __restrict__ symp, const float* __restrict__ dise,
    const float* __restrict__ W21, const float* __restrict__ W22,
    const float* __restrict__ W11, const float* __restrict__ W12,
    const float* __restrict__ Wu, float* __restrict__ out) {
  __shared__ __align__(16) unsigned char smem[81920];
  unsigned short* Wl0p = (unsigned short*)smem;            // 8 KB w21lo
  unsigned short* Wl1p = (unsigned short*)(smem + 8192);   // 8 KB w22lo
  unsigned short* XsB = (unsigned short*)(smem + 16384);   // 64 KB, 8 KB/wave

  const int tid = threadIdx.x;
  const int lane = tid & 63;
  const int wv = __builtin_amdgcn_readfirstlane(tid >> 6);
  const int g = lane >> 4, r15 = lane & 15;
  const int grp = g, c16 = r15;
  const int bpi = (lane & 48) << 2;

  // stage W21lo/W22lo bf16 swizzled: 1024 chunks, 2/thread
#pragma unroll
  for (int i = 0; i < 2; ++i) {
    int c = tid + (i << 9);
    int pl = c >> 9, rc = c & 511;
    int row = rc >> 3, ch = rc & 7;
    const float* src = (pl ? W22 : W21) + row * 64 + ch * 8;
    short8 v;
#pragma unroll
    for (int j = 0; j < 8; ++j) {
      float w = src[j];
      v[j] = (short)f2bf(w - bf2f(f2bf(w)));
    }
    unsigned short* base = pl ? Wl1p : Wl0p;
    *reinterpret_cast<short8*>(&base[row * 64 + ((ch ^ (row & 7)) << 3)]) = v;
  }
  // W21/W22 hi B-frags into 64 VGPRs
  short8 Bh[2][4][2];
#pragma unroll
  for (int mat = 0; mat < 2; ++mat) {
    const float* Wm = mat ? W22 : W21;
#pragma unroll
    for (int nt = 0; nt < 4; ++nt)
#pragma unroll
      for (int ks = 0; ks < 2; ++ks) {
        const float4* p = reinterpret_cast<const float4*>(Wm + (nt * 16 + r15) * 64 + ks * 32 + g * 8);
        float4 va = p[0], vb = p[1];
        short8 h;
        h[0] = (short)f2bf(va.x); h[1] = (short)f2bf(va.y);
        h[2] = (short)f2bf(va.z); h[3] = (short)f2bf(va.w);
        h[4] = (short)f2bf(vb.x); h[5] = (short)f2bf(vb.y);
        h[6] = (short)f2bf(vb.z); h[7] = (short)f2bf(vb.w);
        Bh[mat][nt][ks] = h;
      }
  }
  __syncthreads();

  const int b0w = blockIdx.x * 32 + wv * 4;
  unsigned short* xw = XsB + wv * 4096;
  float s1sum[4] = {0.f, 0.f, 0.f, 0.f};

  int sd = 0;
  if (c16 < K1N) sd = dsd1[(b0w + grp) * K1N + c16];
  unsigned long long ball = __ballot((c16 < K1N) && (sd != 0));
  float c1f = (float)__popcll(ball & (1023ull << (grp << 4)));

  p1_step<4>(0, b0w, lane, grp, c16, r15, g, bpi, dsd2, symp, dise, sd, Wl0p, Wl1p, xw, Bh, s1sum);
  p1_step<4>(4, b0w, lane, grp, c16, r15, g, bpi, dsd2, symp, dise, sd, Wl0p, Wl1p, xw, Bh, s1sum);
  p1_step<2>(8, b0w, lane, grp, c16, r15, g, bpi, dsd2, symp, dise, sd, Wl0p, Wl1p, xw, Bh, s1sum);

  // s1 for elem g stays in registers (cols nt*16 + r15)
  float w1 = nb_w(c1f);
  float s1f[4];
#pragma unroll
  for (int nt = 0; nt < 4; ++nt) s1f[nt] = s1sum[nt] * w1;

  // ---- usu coda: quad-row gather-average, result kept in registers ----
  const int d4 = (lane & 15) << 2;
  f32x4 su4[4];
#pragma unroll
  for (int e = 0; e < 4; ++e) {
    const int b = b0w + e;
    int ui = 0;
    if (lane < MMN) ui = usu1[b * MMN + lane];
    float cnt = (float)__popcll(__ballot(ui != 0));
    f32x4 su = {0.f, 0.f, 0.f, 0.f};
#pragma unroll
    for (int m = 0; m < 48; m += 4) {
      int idx = __shfl(ui, m + grp, 64);
      su += *(const f32x4*)(symp + (idx << 6) + d4);  // symp row 0 is exactly zero
    }
    {
      int idx = __shfl(ui, 48 + grp, 64);
      if (grp < 2) su += *(const f32x4*)(symp + (idx << 6) + d4);
    }
#pragma unroll
    for (int c = 0; c < 4; ++c) {
      su[c] += __shfl_xor(su[c], 16, 64);
      su[c] += __shfl_xor(su[c], 32, 64);
    }
    su4[e] = su * nb_w(cnt);
  }

  // ================= final coda: overlay LDS, 3 matvecs + dot =================
  __syncthreads();  // everyone done with Wl/Xs before overwrite

  float4* lwf4 = (float4*)smem;               // 48 KB: W11,W12,Wu f32 swizzled
  float* xb = (float*)(smem + 49152);         // 24 KB: [8 waves][4 elems][3 planes][64]
  float* xbw = xb + wv * (4 * 3 * 64);

  // stage 3 f32 W matrices: 3072 float4 chunks, 6/thread
#pragma unroll
  for (int i = 0; i < 6; ++i) {
    int c = tid + (i << 9);
    int mt = c >> 10, rc = c & 1023;
    int e = rc >> 4, q = rc & 15;
    const float4* srcp = reinterpret_cast<const float4*>(mt == 0 ? W11 : (mt == 1 ? W12 : Wu));
    lwf4[(mt << 10) | (e << 4) | (q ^ (e & 7))] = srcp[rc];
  }
  // scatter s1 (elem g) and mu (all elems) into xb
#pragma unroll
  for (int nt = 0; nt < 4; ++nt) xbw[(g * 3 + 0) * 64 + nt * 16 + r15] = s1f[nt];
  if (lane < 16) {
#pragma unroll
    for (int e = 0; e < 4; ++e)
      *reinterpret_cast<f32x4*>(&xbw[(e * 3 + 2) * 64 + d4]) = su4[e];
  }
  __syncthreads();  // staged W visible; own-wave xb writes also ordered

  // x1 = s1 + t, x2 = s1 * t (lane = d)
#pragma unroll
  for (int bi = 0; bi < 4; ++bi) {
    int lb = label[b0w + bi];
    float t = dise[(lb << 6) | lane];
    float s1v = xbw[(bi * 3 + 0) * 64 + lane];
    xbw[(bi * 3 + 0) * 64 + lane] = s1v + t;
    xbw[(bi * 3 + 1) * 64 + lane] = s1v * t;
  }
  asm volatile("s_waitcnt lgkmcnt(0)" ::: "memory");

  // crossbar matvec (proven round-3 final): lane = output col e
  float y1[4] = {0.f, 0.f, 0.f, 0.f};
  float y2[4] = {0.f, 0.f, 0.f, 0.f};
  const int swz = lane & 7;
#pragma unroll 4
  for (int q = 0; q < 16; ++q) {
    float4 wa = lwf4[(0 << 10) | (lane << 4) | (q ^ swz)];
    float4 wb = lwf4[(1 << 10) | (lane << 4) | (q ^ swz)];
    float4 wc = lwf4[(2 << 10) | (lane << 4) | (q ^ swz)];
#pragma unroll
    for (int bi = 0; bi < 4; ++bi) {
      float4 xv1 = *reinterpret_cast<const float4*>(&xbw[(bi * 3 + 0) * 64 + (q << 2)]);
      float4 xv2 = *reinterpret_cast<const float4*>(&xbw[(bi * 3 + 1) * 64 + (q << 2)]);
      float4 xv3 = *reinterpret_cast<const float4*>(&xbw[(bi * 3 + 2) * 64 + (q << 2)]);
      fma4(y1[bi], wa, xv1);
      fma4(y1[bi], wb, xv2);
      fma4(y2[bi], wc, xv3);
    }
  }
#pragma unroll
  for (int bi = 0; bi < 4; ++bi) {
    float p = fast_tanh(y1[bi]) * fast_tanh(y2[bi]);
#pragma unroll
    for (int off = 32; off; off >>= 1) p += __shfl_xor(p, off, 64);
    if (lane == 0) out[b0w + bi] = p;
  }
}

extern "C" void kernel_launch(void* const* d_in, const int* in_sizes, int n_in,
                              void* d_out, int out_size, void* d_ws, size_t ws_size,
                              hipStream_t stream) {
  const int* dsd1 = (const int*)d_in[0];
  const int* dsd2 = (const int*)d_in[1];
  const int* usu1 = (const int*)d_in[2];
  const int* label = (const int*)d_in[3];
  const float* symp = (const float*)d_in[4];
  const float* dise = (const float*)d_in[5];
  const float* Wu = (const float*)d_in[6];
  const float* W21 = (const float*)d_in[7];
  const float* W22 = (const float*)d_in[8];
  const float* W11 = (const float*)d_in[9];
  const float* W12 = (const float*)d_in[10];
  float* out = (float*)d_out;

  const int B = in_sizes[3];
  hipLaunchKernelGGL(hgnn_fused, dim3(B / 32), dim3(512), 0, stream,
                     dsd1, dsd2, usu1, label, symp, dise, W21, W22, W11, W12, Wu, out);
}

// Round 15
// 86.668 us; speedup vs baseline: 2.4438x; 1.0081x over previous
//
#include <hip/hip_runtime.h>

#define K1N 10
#define K2N 10
#define MMN 50

typedef __attribute__((ext_vector_type(8))) short short8;
typedef __attribute__((ext_vector_type(4))) float f32x4;
typedef __attribute__((ext_vector_type(4))) unsigned short us16x4;

__device__ __forceinline__ float fast_tanh(float x) {
  x = fminf(fmaxf(x, -15.f), 15.f);
  float e2 = __expf(2.f * x);
  return (e2 - 1.f) * __builtin_amdgcn_rcpf(e2 + 1.f);
}

// reference's _avg_on_real_neighbor weight (exact f32 semantics)
__device__ __forceinline__ float nb_w(float cnt) {
  float w = 1.0f / (cnt + 1e-8f);
  return (w >= 1e8f) ? 0.f : w;
}

// f32 -> bf16 RNE as raw ushort; exact bf16 -> f32
__device__ __forceinline__ unsigned short f2bf(float x) {
  unsigned u = __builtin_bit_cast(unsigned, x);
  return (unsigned short)((u + 0x7FFFu + ((u >> 16) & 1u)) >> 16);
}
__device__ __forceinline__ float bf2f(unsigned short s) {
  return __builtin_bit_cast(float, ((unsigned)s) << 16);
}

__device__ __forceinline__ void fma4(float& y, float4 w, float4 x) {
  y = fmaf(w.x, x.x, y);
  y = fmaf(w.y, x.y, y);
  y = fmaf(w.z, x.z, y);
  y = fmaf(w.w, x.w, y);
}

#define MFMA16(A, B, C) __builtin_amdgcn_mfma_f32_16x16x32_bf16(A, B, C, 0, 0, 0)

// one phase-1 k-chunk, QUAD-ROW gather (round-13 proven), indices PRELOADED (i4 param).
template <int KQ>
__device__ __forceinline__ void p1_step(
    int kbase, int b0w, int lane, int grp, int c16, int r15, int g, int bpi,
    int4 i4,
    const float* __restrict__ symp, const float* __restrict__ dise,
    int sd, const unsigned short* __restrict__ Wl0, const unsigned short* __restrict__ Wl1,
    unsigned short* xw, const short8 (&Bh)[2][4][2],
    float (&s1sum)[4]) {
  int idxa[4] = {i4.x, i4.y, i4.z, i4.w};

  f32x4 acc[KQ], esv[KQ];
  int c2[KQ];
  int sxv[KQ];
#pragma unroll
  for (int kq = 0; kq < KQ; ++kq) {
    acc[kq] = (f32x4){0.f, 0.f, 0.f, 0.f};
    c2[kq] = 0;
    sxv[kq] = __builtin_amdgcn_ds_bpermute(bpi + ((kbase + kq) << 2), sd);
  }
#pragma unroll
  for (int kq = 0; kq < KQ; ++kq)
    esv[kq] = *reinterpret_cast<const f32x4*>(symp + (sxv[kq] << 6) + (c16 << 2));
#pragma unroll
  for (int m = 0; m < K2N; ++m) {
#pragma unroll
    for (int kq = 0; kq < KQ; ++kq) {
      const int f = kq * K2N + m;
      int idxv = __builtin_amdgcn_ds_bpermute(bpi + ((f >> 2) << 2), idxa[f & 3]);
      c2[kq] += (idxv != 0);
      acc[kq] += *reinterpret_cast<const f32x4*>(dise + (idxv << 6) + (c16 << 2));  // row 0 = 0
    }
  }

#pragma unroll
  for (int kq = 0; kq < KQ; ++kq) {
    float w2 = (c2[kq] == 0) ? 0.f : __builtin_amdgcn_rcpf((float)c2[kq] + 1e-8f);
    f32x4 ad = acc[kq] * w2;
    f32x4 t1 = esv[kq] + ad;
    f32x4 t2 = esv[kq] * ad;
    const int u = (grp << 2) | kq;
    const int off = u * 64 + (((c16 >> 1) ^ (u & 7)) << 3) + ((c16 & 1) << 2);
    us16x4 h1, l1, h2, l2;
#pragma unroll
    for (int c = 0; c < 4; ++c) {
      unsigned short hh = f2bf(t1[c]);
      h1[c] = hh;
      l1[c] = f2bf(t1[c] - bf2f(hh));
      unsigned short h2c = f2bf(t2[c]);
      h2[c] = h2c;
      l2[c] = f2bf(t2[c] - bf2f(h2c));
    }
    *reinterpret_cast<us16x4*>(xw + off) = h1;
    *reinterpret_cast<us16x4*>(xw + 1024 + off) = l1;
    *reinterpret_cast<us16x4*>(xw + 2048 + off) = h2;
    *reinterpret_cast<us16x4*>(xw + 3072 + off) = l2;
  }
  asm volatile("s_waitcnt lgkmcnt(0)" ::: "memory");

  f32x4 acc4[4];
#pragma unroll
  for (int nt = 0; nt < 4; ++nt) acc4[nt] = (f32x4){0.f, 0.f, 0.f, 0.f};
#pragma unroll
  for (int ks = 0; ks < 2; ++ks) {
    const int aoff = r15 * 64 + (((4 * ks + g) ^ (r15 & 7)) << 3);
    short8 a1h = *(const short8*)(xw + aoff);
    short8 a1l = *(const short8*)(xw + 1024 + aoff);
    short8 a2h = *(const short8*)(xw + 2048 + aoff);
    short8 a2l = *(const short8*)(xw + 3072 + aoff);
#pragma unroll
    for (int nt = 0; nt < 4; ++nt) {
      const int wb = (nt * 16 + r15) * 64 + (((4 * ks + g) ^ (r15 & 7)) << 3);
      short8 w21l = *(const short8*)(Wl0 + wb);
      short8 w22l = *(const short8*)(Wl1 + wb);
      acc4[nt] = MFMA16(a1h, Bh[0][nt][ks], acc4[nt]);
      acc4[nt] = MFMA16(a1l, Bh[0][nt][ks], acc4[nt]);
      acc4[nt] = MFMA16(a1h, w21l, acc4[nt]);
      acc4[nt] = MFMA16(a2h, Bh[1][nt][ks], acc4[nt]);
      acc4[nt] = MFMA16(a2l, Bh[1][nt][ks], acc4[nt]);
      acc4[nt] = MFMA16(a2h, w22l, acc4[nt]);
    }
  }
#pragma unroll
  for (int rr = 0; rr < KQ; ++rr) {
    float ta[4], ss = 0.f;
#pragma unroll
    for (int nt = 0; nt < 4; ++nt) {
      ta[nt] = fast_tanh(acc4[nt][rr]);
      ss = fmaf(ta[nt], ta[nt], ss);
    }
    ss += __shfl_xor(ss, 1, 64); ss += __shfl_xor(ss, 2, 64);
    ss += __shfl_xor(ss, 4, 64); ss += __shfl_xor(ss, 8, 64);
    float inv = __builtin_amdgcn_rcpf(fmaxf(sqrtf(ss), 1e-12f));
#pragma unroll
    for (int nt = 0; nt < 4; ++nt) s1sum[nt] = fmaf(ta[nt], inv, s1sum[nt]);
  }
}

// ====== FULLY FUSED (round-14) + index-preload pipelining (round-15) ======
__global__ __launch_bounds__(512, 2) void hgnn_fused(
    const int* __restrict__ dsd1, const int* __restrict__ dsd2,
    const int* __restrict__ usu1, const int* __restrict__ label,
    const float* __restrict__ symp, const float* __restrict__ dise,
    const float* __restrict__ W21, const float* __restrict__ W22,
    const float* __restrict__ W11, const float* __restrict__ W12,
    const float* __restrict__ Wu, float* __restrict__ out) {
  __shared__ __align__(16) unsigned char smem[81920];
  unsigned short* Wl0p = (unsigned short*)smem;            // 8 KB w21lo
  unsigned short* Wl1p = (unsigned short*)(smem + 8192);   // 8 KB w22lo
  unsigned short* XsB = (unsigned short*)(smem + 16384);   // 64 KB, 8 KB/wave

  const int tid = threadIdx.x;
  const int lane = tid & 63;
  const int wv = __builtin_amdgcn_readfirstlane(tid >> 6);
  const int g = lane >> 4, r15 = lane & 15;
  const int grp = g, c16 = r15;
  const int bpi = (lane & 48) << 2;

  const int b0w = blockIdx.x * 32 + wv * 4;

  // ---- EARLY index preloads: all 3 steps' dsd2 quads + dsd1 + usu indices ----
  const int* d2base = dsd2 + (b0w + grp) * (K1N * K2N);
  int4 i4a = {0, 0, 0, 0}, i4b = {0, 0, 0, 0}, i4c = {0, 0, 0, 0};
  if (c16 < 10) {
    i4a = *reinterpret_cast<const int4*>(d2base + (c16 << 2));
    i4b = *reinterpret_cast<const int4*>(d2base + 40 + (c16 << 2));
  }
  if (c16 < 5) i4c = *reinterpret_cast<const int4*>(d2base + 80 + (c16 << 2));
  int sd = 0;
  if (c16 < K1N) sd = dsd1[(b0w + grp) * K1N + c16];
  int uie[4];
#pragma unroll
  for (int e = 0; e < 4; ++e) {
    int v = 0;
    if (lane < MMN) v = usu1[(b0w + e) * MMN + lane];
    uie[e] = v;
  }

  // stage W21lo/W22lo bf16 swizzled: 1024 chunks, 2/thread
#pragma unroll
  for (int i = 0; i < 2; ++i) {
    int c = tid + (i << 9);
    int pl = c >> 9, rc = c & 511;
    int row = rc >> 3, ch = rc & 7;
    const float* src = (pl ? W22 : W21) + row * 64 + ch * 8;
    short8 v;
#pragma unroll
    for (int j = 0; j < 8; ++j) {
      float w = src[j];
      v[j] = (short)f2bf(w - bf2f(f2bf(w)));
    }
    unsigned short* base = pl ? Wl1p : Wl0p;
    *reinterpret_cast<short8*>(&base[row * 64 + ((ch ^ (row & 7)) << 3)]) = v;
  }
  // W21/W22 hi B-frags into 64 VGPRs
  short8 Bh[2][4][2];
#pragma unroll
  for (int mat = 0; mat < 2; ++mat) {
    const float* Wm = mat ? W22 : W21;
#pragma unroll
    for (int nt = 0; nt < 4; ++nt)
#pragma unroll
      for (int ks = 0; ks < 2; ++ks) {
        const float4* p = reinterpret_cast<const float4*>(Wm + (nt * 16 + r15) * 64 + ks * 32 + g * 8);
        float4 va = p[0], vb = p[1];
        short8 h;
        h[0] = (short)f2bf(va.x); h[1] = (short)f2bf(va.y);
        h[2] = (short)f2bf(va.z); h[3] = (short)f2bf(va.w);
        h[4] = (short)f2bf(vb.x); h[5] = (short)f2bf(vb.y);
        h[6] = (short)f2bf(vb.z); h[7] = (short)f2bf(vb.w);
        Bh[mat][nt][ks] = h;
      }
  }
  __syncthreads();

  unsigned short* xw = XsB + wv * 4096;
  float s1sum[4] = {0.f, 0.f, 0.f, 0.f};

  unsigned long long ball = __ballot((c16 < K1N) && (sd != 0));
  float c1f = (float)__popcll(ball & (1023ull << (grp << 4)));

  p1_step<4>(0, b0w, lane, grp, c16, r15, g, bpi, i4a, symp, dise, sd, Wl0p, Wl1p, xw, Bh, s1sum);
  p1_step<4>(4, b0w, lane, grp, c16, r15, g, bpi, i4b, symp, dise, sd, Wl0p, Wl1p, xw, Bh, s1sum);
  p1_step<2>(8, b0w, lane, grp, c16, r15, g, bpi, i4c, symp, dise, sd, Wl0p, Wl1p, xw, Bh, s1sum);

  // s1 for elem g stays in registers (cols nt*16 + r15)
  float w1 = nb_w(c1f);
  float s1f[4];
#pragma unroll
  for (int nt = 0; nt < 4; ++nt) s1f[nt] = s1sum[nt] * w1;

  // ---- usu coda: quad-row gather, elem-interleaved (4 independent chains) ----
  const int d4 = (lane & 15) << 2;
  f32x4 su4[4];
  float cnt4[4];
#pragma unroll
  for (int e = 0; e < 4; ++e) {
    cnt4[e] = (float)__popcll(__ballot(uie[e] != 0));
    su4[e] = (f32x4){0.f, 0.f, 0.f, 0.f};
  }
#pragma unroll
  for (int m = 0; m < 48; m += 4) {
#pragma unroll
    for (int e = 0; e < 4; ++e) {
      int idx = __shfl(uie[e], m + grp, 64);
      su4[e] += *(const f32x4*)(symp + (idx << 6) + d4);  // symp row 0 is exactly zero
    }
  }
#pragma unroll
  for (int e = 0; e < 4; ++e) {
    int idx = __shfl(uie[e], 48 + grp, 64);
    if (grp < 2) su4[e] += *(const f32x4*)(symp + (idx << 6) + d4);
  }
#pragma unroll
  for (int e = 0; e < 4; ++e) {
#pragma unroll
    for (int c = 0; c < 4; ++c) {
      su4[e][c] += __shfl_xor(su4[e][c], 16, 64);
      su4[e][c] += __shfl_xor(su4[e][c], 32, 64);
    }
    su4[e] = su4[e] * nb_w(cnt4[e]);
  }

  // ================= final coda: overlay LDS, 3 matvecs + dot =================
  __syncthreads();  // everyone done with Wl/Xs before overwrite

  float4* lwf4 = (float4*)smem;               // 48 KB: W11,W12,Wu f32 swizzled
  float* xb = (float*)(smem + 49152);         // 24 KB: [8 waves][4 elems][3 planes][64]
  float* xbw = xb + wv * (4 * 3 * 64);

  // stage 3 f32 W matrices: 3072 float4 chunks, 6/thread
#pragma unroll
  for (int i = 0; i < 6; ++i) {
    int c = tid + (i << 9);
    int mt = c >> 10, rc = c & 1023;
    int e = rc >> 4, q = rc & 15;
    const float4* srcp = reinterpret_cast<const float4*>(mt == 0 ? W11 : (mt == 1 ? W12 : Wu));
    lwf4[(mt << 10) | (e << 4) | (q ^ (e & 7))] = srcp[rc];
  }
  // scatter s1 (elem g) and mu (all elems) into xb
#pragma unroll
  for (int nt = 0; nt < 4; ++nt) xbw[(g * 3 + 0) * 64 + nt * 16 + r15] = s1f[nt];
  if (lane < 16) {
#pragma unroll
    for (int e = 0; e < 4; ++e)
      *reinterpret_cast<f32x4*>(&xbw[(e * 3 + 2) * 64 + d4]) = su4[e];
  }
  __syncthreads();  // staged W visible; own-wave xb writes also ordered

  // x1 = s1 + t, x2 = s1 * t (lane = d)
#pragma unroll
  for (int bi = 0; bi < 4; ++bi) {
    int lb = label[b0w + bi];
    float t = dise[(lb << 6) | lane];
    float s1v = xbw[(bi * 3 + 0) * 64 + lane];
    xbw[(bi * 3 + 0) * 64 + lane] = s1v + t;
    xbw[(bi * 3 + 1) * 64 + lane] = s1v * t;
  }
  asm volatile("s_waitcnt lgkmcnt(0)" ::: "memory");

  // crossbar matvec (proven round-3 final): lane = output col e
  float y1[4] = {0.f, 0.f, 0.f, 0.f};
  float y2[4] = {0.f, 0.f, 0.f, 0.f};
  const int swz = lane & 7;
#pragma unroll 4
  for (int q = 0; q < 16; ++q) {
    float4 wa = lwf4[(0 << 10) | (lane << 4) | (q ^ swz)];
    float4 wb = lwf4[(1 << 10) | (lane << 4) | (q ^ swz)];
    float4 wc = lwf4[(2 << 10) | (lane << 4) | (q ^ swz)];
#pragma unroll
    for (int bi = 0; bi < 4; ++bi) {
      float4 xv1 = *reinterpret_cast<const float4*>(&xbw[(bi * 3 + 0) * 64 + (q << 2)]);
      float4 xv2 = *reinterpret_cast<const float4*>(&xbw[(bi * 3 + 1) * 64 + (q << 2)]);
      float4 xv3 = *reinterpret_cast<const float4*>(&xbw[(bi * 3 + 2) * 64 + (q << 2)]);
      fma4(y1[bi], wa, xv1);
      fma4(y1[bi], wb, xv2);
      fma4(y2[bi], wc, xv3);
    }
  }
#pragma unroll
  for (int bi = 0; bi < 4; ++bi) {
    float p = fast_tanh(y1[bi]) * fast_tanh(y2[bi]);
#pragma unroll
    for (int off = 32; off; off >>= 1) p += __shfl_xor(p, off, 64);
    if (lane == 0) out[b0w + bi] = p;
  }
}

extern "C" void kernel_launch(void* const* d_in, const int* in_sizes, int n_in,
                              void* d_out, int out_size, void* d_ws, size_t ws_size,
                              hipStream_t stream) {
  const int* dsd1 = (const int*)d_in[0];
  const int* dsd2 = (const int*)d_in[1];
  const int* usu1 = (const int*)d_in[2];
  const int* label = (const int*)d_in[3];
  const float* symp = (const float*)d_in[4];
  const float* dise = (const float*)d_in[5];
  const float* Wu = (const float*)d_in[6];
  const float* W21 = (const float*)d_in[7];
  const float* W22 = (const float*)d_in[8];
  const float* W11 = (const float*)d_in[9];
  const float* W12 = (const float*)d_in[10];
  float* out = (float*)d_out;

  const int B = in_sizes[3];
  hipLaunchKernelGGL(hgnn_fused, dim3(B / 32), dim3(512), 0, stream,
                     dsd1, dsd2, usu1, label, symp, dise, W21, W22, W11, W12, Wu, out);
}

// Round 16
// 82.179 us; speedup vs baseline: 2.5773x; 1.0546x over previous
//
#include <hip/hip_runtime.h>
#include <hip/hip_bf16.h>

#define K1N 10
#define K2N 10
#define MMN 50

typedef __attribute__((ext_vector_type(8))) short short8;
typedef __attribute__((ext_vector_type(4))) float f32x4;
typedef __attribute__((ext_vector_type(4))) unsigned short us16x4;

__device__ __forceinline__ float fast_tanh(float x) {
  x = fminf(fmaxf(x, -15.f), 15.f);
  float e2 = __expf(2.f * x);
  return (e2 - 1.f) * __builtin_amdgcn_rcpf(e2 + 1.f);
}

// reference's _avg_on_real_neighbor weight (exact f32 semantics)
__device__ __forceinline__ float nb_w(float cnt) {
  float w = 1.0f / (cnt + 1e-8f);
  return (w >= 1e8f) ? 0.f : w;
}

// f32 -> bf16 via native cast (compiler emits v_cvt_pk_bf16_f32, RNE); exact bf16 -> f32
__device__ __forceinline__ unsigned short f2bf(float x) {
  __hip_bfloat16 b = __float2bfloat16(x);
  return __builtin_bit_cast(unsigned short, b);
}
__device__ __forceinline__ float bf2f(unsigned short s) {
  return __builtin_bit_cast(float, ((unsigned)s) << 16);
}

__device__ __forceinline__ void fma4(float& y, float4 w, float4 x) {
  y = fmaf(w.x, x.x, y);
  y = fmaf(w.y, x.y, y);
  y = fmaf(w.z, x.z, y);
  y = fmaf(w.w, x.w, y);
}

#define MFMA16(A, B, C) __builtin_amdgcn_mfma_f32_16x16x32_bf16(A, B, C, 0, 0, 0)

// one phase-1 k-chunk, QUAD-ROW gather, 3 X planes {t1h,t1l,t2h}, 4 MFMAs/(ks,nt).
// Error budget: t2~3e-3 scale => dropped t2l (~1e-6) and t2h*W22lo (~2.4e-6) are
// negligible vs 1.7e-4 threshold; t1's two correction terms kept.
template <int KQ>
__device__ __forceinline__ void p1_step(
    int kbase, int b0w, int lane, int grp, int c16, int r15, int g, int bpi,
    int4 i4,
    const float* __restrict__ symp, const float* __restrict__ dise,
    int sd, const unsigned short* __restrict__ Wl0 /* w21lo */,
    unsigned short* xw, const short8 (&Bh)[2][4][2],
    float (&s1sum)[4]) {
  int idxa[4] = {i4.x, i4.y, i4.z, i4.w};

  f32x4 acc[KQ], esv[KQ];
  int c2[KQ];
  int sxv[KQ];
#pragma unroll
  for (int kq = 0; kq < KQ; ++kq) {
    acc[kq] = (f32x4){0.f, 0.f, 0.f, 0.f};
    c2[kq] = 0;
    sxv[kq] = __builtin_amdgcn_ds_bpermute(bpi + ((kbase + kq) << 2), sd);
  }
#pragma unroll
  for (int kq = 0; kq < KQ; ++kq)
    esv[kq] = *reinterpret_cast<const f32x4*>(symp + (sxv[kq] << 6) + (c16 << 2));
#pragma unroll
  for (int m = 0; m < K2N; ++m) {
#pragma unroll
    for (int kq = 0; kq < KQ; ++kq) {
      const int f = kq * K2N + m;
      int idxv = __builtin_amdgcn_ds_bpermute(bpi + ((f >> 2) << 2), idxa[f & 3]);
      c2[kq] += (idxv != 0);
      acc[kq] += *reinterpret_cast<const f32x4*>(dise + (idxv << 6) + (c16 << 2));  // row 0 = 0
    }
  }

#pragma unroll
  for (int kq = 0; kq < KQ; ++kq) {
    float w2 = (c2[kq] == 0) ? 0.f : __builtin_amdgcn_rcpf((float)c2[kq] + 1e-8f);
    f32x4 ad = acc[kq] * w2;
    f32x4 t1 = esv[kq] + ad;
    f32x4 t2 = esv[kq] * ad;
    const int u = (grp << 2) | kq;
    const int off = u * 64 + (((c16 >> 1) ^ (u & 7)) << 3) + ((c16 & 1) << 2);
    us16x4 h1, l1, h2;
#pragma unroll
    for (int c = 0; c < 4; ++c) {
      unsigned short hh = f2bf(t1[c]);
      h1[c] = hh;
      l1[c] = f2bf(t1[c] - bf2f(hh));
      h2[c] = f2bf(t2[c]);
    }
    *reinterpret_cast<us16x4*>(xw + off) = h1;
    *reinterpret_cast<us16x4*>(xw + 1024 + off) = l1;
    *reinterpret_cast<us16x4*>(xw + 2048 + off) = h2;
  }
  asm volatile("s_waitcnt lgkmcnt(0)" ::: "memory");

  f32x4 acc4[4];
#pragma unroll
  for (int nt = 0; nt < 4; ++nt) acc4[nt] = (f32x4){0.f, 0.f, 0.f, 0.f};
#pragma unroll
  for (int ks = 0; ks < 2; ++ks) {
    const int aoff = r15 * 64 + (((4 * ks + g) ^ (r15 & 7)) << 3);
    short8 a1h = *(const short8*)(xw + aoff);
    short8 a1l = *(const short8*)(xw + 1024 + aoff);
    short8 a2h = *(const short8*)(xw + 2048 + aoff);
#pragma unroll
    for (int nt = 0; nt < 4; ++nt) {
      const int wb = (nt * 16 + r15) * 64 + (((4 * ks + g) ^ (r15 & 7)) << 3);
      short8 w21l = *(const short8*)(Wl0 + wb);
      acc4[nt] = MFMA16(a1h, Bh[0][nt][ks], acc4[nt]);
      acc4[nt] = MFMA16(a1l, Bh[0][nt][ks], acc4[nt]);
      acc4[nt] = MFMA16(a1h, w21l, acc4[nt]);
      acc4[nt] = MFMA16(a2h, Bh[1][nt][ks], acc4[nt]);
    }
  }
#pragma unroll
  for (int rr = 0; rr < KQ; ++rr) {
    float ta[4], ss = 0.f;
#pragma unroll
    for (int nt = 0; nt < 4; ++nt) {
      ta[nt] = fast_tanh(acc4[nt][rr]);
      ss = fmaf(ta[nt], ta[nt], ss);
    }
    ss += __shfl_xor(ss, 1, 64); ss += __shfl_xor(ss, 2, 64);
    ss += __shfl_xor(ss, 4, 64); ss += __shfl_xor(ss, 8, 64);
    float inv = __builtin_amdgcn_rcpf(fmaxf(sqrtf(ss), 1e-12f));
#pragma unroll
    for (int nt = 0; nt < 4; ++nt) s1sum[nt] = fmaf(ta[nt], inv, s1sum[nt]);
  }
}

// ====== FULLY FUSED + slim split: 3 X planes, W21lo-only LDS, 32 MFMA/step ======
__global__ __launch_bounds__(512, 2) void hgnn_fused(
    const int* __restrict__ dsd1, const int* __restrict__ dsd2,
    const int* __restrict__ usu1, const int* __restrict__ label,
    const float* __restrict__ symp, const float* __restrict__ dise,
    const float* __restrict__ W21, const float* __restrict__ W22,
    const float* __restrict__ W11, const float* __restrict__ W12,
    const float* __restrict__ Wu, float* __restrict__ out) {
  __shared__ __align__(16) unsigned char smem[73728];
  unsigned short* Wl0p = (unsigned short*)smem;           // 8 KB w21lo
  unsigned short* XsB = (unsigned short*)(smem + 8192);   // 48 KB, 6 KB/wave

  const int tid = threadIdx.x;
  const int lane = tid & 63;
  const int wv = __builtin_amdgcn_readfirstlane(tid >> 6);
  const int g = lane >> 4, r15 = lane & 15;
  const int grp = g, c16 = r15;
  const int bpi = (lane & 48) << 2;

  const int b0w = blockIdx.x * 32 + wv * 4;

  // ---- EARLY index preloads: all 3 steps' dsd2 quads + dsd1 + usu indices ----
  const int* d2base = dsd2 + (b0w + grp) * (K1N * K2N);
  int4 i4a = {0, 0, 0, 0}, i4b = {0, 0, 0, 0}, i4c = {0, 0, 0, 0};
  if (c16 < 10) {
    i4a = *reinterpret_cast<const int4*>(d2base + (c16 << 2));
    i4b = *reinterpret_cast<const int4*>(d2base + 40 + (c16 << 2));
  }
  if (c16 < 5) i4c = *reinterpret_cast<const int4*>(d2base + 80 + (c16 << 2));
  int sd = 0;
  if (c16 < K1N) sd = dsd1[(b0w + grp) * K1N + c16];
  int uie[4];
#pragma unroll
  for (int e = 0; e < 4; ++e) {
    int v = 0;
    if (lane < MMN) v = usu1[(b0w + e) * MMN + lane];
    uie[e] = v;
  }

  // stage W21lo bf16 swizzled: 512 chunks, 1/thread
  {
    int c = tid;
    int row = c >> 3, ch = c & 7;
    const float* src = W21 + row * 64 + ch * 8;
    short8 v;
#pragma unroll
    for (int j = 0; j < 8; ++j) {
      float w = src[j];
      v[j] = (short)f2bf(w - bf2f(f2bf(w)));
    }
    *reinterpret_cast<short8*>(&Wl0p[row * 64 + ((ch ^ (row & 7)) << 3)]) = v;
  }
  // W21/W22 hi B-frags into 64 VGPRs
  short8 Bh[2][4][2];
#pragma unroll
  for (int mat = 0; mat < 2; ++mat) {
    const float* Wm = mat ? W22 : W21;
#pragma unroll
    for (int nt = 0; nt < 4; ++nt)
#pragma unroll
      for (int ks = 0; ks < 2; ++ks) {
        const float4* p = reinterpret_cast<const float4*>(Wm + (nt * 16 + r15) * 64 + ks * 32 + g * 8);
        float4 va = p[0], vb = p[1];
        short8 h;
        h[0] = (short)f2bf(va.x); h[1] = (short)f2bf(va.y);
        h[2] = (short)f2bf(va.z); h[3] = (short)f2bf(va.w);
        h[4] = (short)f2bf(vb.x); h[5] = (short)f2bf(vb.y);
        h[6] = (short)f2bf(vb.z); h[7] = (short)f2bf(vb.w);
        Bh[mat][nt][ks] = h;
      }
  }
  __syncthreads();

  unsigned short* xw = XsB + wv * 3072;
  float s1sum[4] = {0.f, 0.f, 0.f, 0.f};

  unsigned long long ball = __ballot((c16 < K1N) && (sd != 0));
  float c1f = (float)__popcll(ball & (1023ull << (grp << 4)));

  p1_step<4>(0, b0w, lane, grp, c16, r15, g, bpi, i4a, symp, dise, sd, Wl0p, xw, Bh, s1sum);
  p1_step<4>(4, b0w, lane, grp, c16, r15, g, bpi, i4b, symp, dise, sd, Wl0p, xw, Bh, s1sum);
  p1_step<2>(8, b0w, lane, grp, c16, r15, g, bpi, i4c, symp, dise, sd, Wl0p, xw, Bh, s1sum);

  // s1 for elem g stays in registers (cols nt*16 + r15)
  float w1 = nb_w(c1f);
  float s1f[4];
#pragma unroll
  for (int nt = 0; nt < 4; ++nt) s1f[nt] = s1sum[nt] * w1;

  // ---- usu coda: quad-row gather, elem-interleaved (4 independent chains) ----
  const int d4 = (lane & 15) << 2;
  f32x4 su4[4];
  float cnt4[4];
#pragma unroll
  for (int e = 0; e < 4; ++e) {
    cnt4[e] = (float)__popcll(__ballot(uie[e] != 0));
    su4[e] = (f32x4){0.f, 0.f, 0.f, 0.f};
  }
#pragma unroll
  for (int m = 0; m < 48; m += 4) {
#pragma unroll
    for (int e = 0; e < 4; ++e) {
      int idx = __shfl(uie[e], m + grp, 64);
      su4[e] += *(const f32x4*)(symp + (idx << 6) + d4);  // symp row 0 is exactly zero
    }
  }
#pragma unroll
  for (int e = 0; e < 4; ++e) {
    int idx = __shfl(uie[e], 48 + grp, 64);
    if (grp < 2) su4[e] += *(const f32x4*)(symp + (idx << 6) + d4);
  }
#pragma unroll
  for (int e = 0; e < 4; ++e) {
#pragma unroll
    for (int c = 0; c < 4; ++c) {
      su4[e][c] += __shfl_xor(su4[e][c], 16, 64);
      su4[e][c] += __shfl_xor(su4[e][c], 32, 64);
    }
    su4[e] = su4[e] * nb_w(cnt4[e]);
  }

  // ================= final coda: overlay LDS, 3 matvecs + dot =================
  __syncthreads();  // everyone done with Wl/Xs before overwrite

  float4* lwf4 = (float4*)smem;               // 48 KB: W11,W12,Wu f32 swizzled
  float* xb = (float*)(smem + 49152);         // 24 KB: [8 waves][4 elems][3 planes][64]
  float* xbw = xb + wv * (4 * 3 * 64);

  // stage 3 f32 W matrices: 3072 float4 chunks, 6/thread
#pragma unroll
  for (int i = 0; i < 6; ++i) {
    int c = tid + (i << 9);
    int mt = c >> 10, rc = c & 1023;
    int e = rc >> 4, q = rc & 15;
    const float4* srcp = reinterpret_cast<const float4*>(mt == 0 ? W11 : (mt == 1 ? W12 : Wu));
    lwf4[(mt << 10) | (e << 4) | (q ^ (e & 7))] = srcp[rc];
  }
  // scatter s1 (elem g) and mu (all elems) into xb
#pragma unroll
  for (int nt = 0; nt < 4; ++nt) xbw[(g * 3 + 0) * 64 + nt * 16 + r15] = s1f[nt];
  if (lane < 16) {
#pragma unroll
    for (int e = 0; e < 4; ++e)
      *reinterpret_cast<f32x4*>(&xbw[(e * 3 + 2) * 64 + d4]) = su4[e];
  }
  __syncthreads();  // staged W visible; own-wave xb writes also ordered

  // x1 = s1 + t, x2 = s1 * t (lane = d)
#pragma unroll
  for (int bi = 0; bi < 4; ++bi) {
    int lb = label[b0w + bi];
    float t = dise[(lb << 6) | lane];
    float s1v = xbw[(bi * 3 + 0) * 64 + lane];
    xbw[(bi * 3 + 0) * 64 + lane] = s1v + t;
    xbw[(bi * 3 + 1) * 64 + lane] = s1v * t;
  }
  asm volatile("s_waitcnt lgkmcnt(0)" ::: "memory");

  // crossbar matvec (proven round-3 final): lane = output col e
  float y1[4] = {0.f, 0.f, 0.f, 0.f};
  float y2[4] = {0.f, 0.f, 0.f, 0.f};
  const int swz = lane & 7;
#pragma unroll 4
  for (int q = 0; q < 16; ++q) {
    float4 wa = lwf4[(0 << 10) | (lane << 4) | (q ^ swz)];
    float4 wb = lwf4[(1 << 10) | (lane << 4) | (q ^ swz)];
    float4 wc = lwf4[(2 << 10) | (lane << 4) | (q ^ swz)];
#pragma unroll
    for (int bi = 0; bi < 4; ++bi) {
      float4 xv1 = *reinterpret_cast<const float4*>(&xbw[(bi * 3 + 0) * 64 + (q << 2)]);
      float4 xv2 = *reinterpret_cast<const float4*>(&xbw[(bi * 3 + 1) * 64 + (q << 2)]);
      float4 xv3 = *reinterpret_cast<const float4*>(&xbw[(bi * 3 + 2) * 64 + (q << 2)]);
      fma4(y1[bi], wa, xv1);
      fma4(y1[bi], wb, xv2);
      fma4(y2[bi], wc, xv3);
    }
  }
#pragma unroll
  for (int bi = 0; bi < 4; ++bi) {
    float p = fast_tanh(y1[bi]) * fast_tanh(y2[bi]);
#pragma unroll
    for (int off = 32; off; off >>= 1) p += __shfl_xor(p, off, 64);
    if (lane == 0) out[b0w + bi] = p;
  }
}

extern "C" void kernel_launch(void* const* d_in, const int* in_sizes, int n_in,
                              void* d_out, int out_size, void* d_ws, size_t ws_size,
                              hipStream_t stream) {
  const int* dsd1 = (const int*)d_in[0];
  const int* dsd2 = (const int*)d_in[1];
  const int* usu1 = (const int*)d_in[2];
  const int* label = (const int*)d_in[3];
  const float* symp = (const float*)d_in[4];
  const float* dise = (const float*)d_in[5];
  const float* Wu = (const float*)d_in[6];
  const float* W21 = (const float*)d_in[7];
  const float* W22 = (const float*)d_in[8];
  const float* W11 = (const float*)d_in[9];
  const float* W12 = (const float*)d_in[10];
  float* out = (float*)d_out;

  const int B = in_sizes[3];
  hipLaunchKernelGGL(hgnn_fused, dim3(B / 32), dim3(512), 0, stream,
                     dsd1, dsd2, usu1, label, symp, dise, W21, W22, W11, W12, Wu, out);
}

// Round 17
// 68.536 us; speedup vs baseline: 3.0904x; 1.1991x over previous
//
#include <hip/hip_runtime.h>
#include <hip/hip_bf16.h>

#define K1N 10
#define K2N 10
#define MMN 50

typedef __attribute__((ext_vector_type(8))) short short8;
typedef __attribute__((ext_vector_type(4))) float f32x4;
typedef __attribute__((ext_vector_type(4))) unsigned short us16x4;

__device__ __forceinline__ float fast_tanh(float x) {
  x = fminf(fmaxf(x, -15.f), 15.f);
  float e2 = __expf(2.f * x);
  return (e2 - 1.f) * __builtin_amdgcn_rcpf(e2 + 1.f);
}

// reference's _avg_on_real_neighbor weight (exact f32 semantics)
__device__ __forceinline__ float nb_w(float cnt) {
  float w = 1.0f / (cnt + 1e-8f);
  return (w >= 1e8f) ? 0.f : w;
}

// f32 -> bf16 via native cast (compiler emits v_cvt_pk_bf16_f32, RNE); exact bf16 -> f32
__device__ __forceinline__ unsigned short f2bf(float x) {
  __hip_bfloat16 b = __float2bfloat16(x);
  return __builtin_bit_cast(unsigned short, b);
}
__device__ __forceinline__ float bf2f(unsigned short s) {
  return __builtin_bit_cast(float, ((unsigned)s) << 16);
}

__device__ __forceinline__ void fma4(float& y, float4 w, float4 x) {
  y = fmaf(w.x, x.x, y);
  y = fmaf(w.y, x.y, y);
  y = fmaf(w.z, x.z, y);
  y = fmaf(w.w, x.w, y);
}

#define MFMA16(A, B, C) __builtin_amdgcn_mfma_f32_16x16x32_bf16(A, B, C, 0, 0, 0)

// one phase-1 k-chunk, QUAD-ROW gather, 3 X planes {t1h,t1l,t2h}.
// W entirely in LDS (w21h/w21l/w22h planes) -> ~64 VGPRs freed for gather MLP.
// NO manual lgkmcnt barriers: same-wave DS-pipe ordering + compiler waits suffice,
// and their absence lets the compiler hoist next-step gathers over this MFMA phase.
template <int KQ>
__device__ __forceinline__ void p1_step(
    int kbase, int b0w, int lane, int grp, int c16, int r15, int g, int bpi,
    int4 i4,
    const float* __restrict__ symp, const float* __restrict__ dise,
    int sd, const unsigned short* __restrict__ Wl,
    unsigned short* xw, float (&s1sum)[4]) {
  int idxa[4] = {i4.x, i4.y, i4.z, i4.w};

  f32x4 acc[KQ], esv[KQ];
  int c2[KQ];
  int sxv[KQ];
#pragma unroll
  for (int kq = 0; kq < KQ; ++kq) {
    acc[kq] = (f32x4){0.f, 0.f, 0.f, 0.f};
    c2[kq] = 0;
    sxv[kq] = __builtin_amdgcn_ds_bpermute(bpi + ((kbase + kq) << 2), sd);
  }
#pragma unroll
  for (int kq = 0; kq < KQ; ++kq)
    esv[kq] = *reinterpret_cast<const f32x4*>(symp + (sxv[kq] << 6) + (c16 << 2));
#pragma unroll
  for (int m = 0; m < K2N; ++m) {
#pragma unroll
    for (int kq = 0; kq < KQ; ++kq) {
      const int f = kq * K2N + m;
      int idxv = __builtin_amdgcn_ds_bpermute(bpi + ((f >> 2) << 2), idxa[f & 3]);
      c2[kq] += (idxv != 0);
      acc[kq] += *reinterpret_cast<const f32x4*>(dise + (idxv << 6) + (c16 << 2));  // row 0 = 0
    }
  }

#pragma unroll
  for (int kq = 0; kq < KQ; ++kq) {
    float w2 = (c2[kq] == 0) ? 0.f : __builtin_amdgcn_rcpf((float)c2[kq] + 1e-8f);
    f32x4 ad = acc[kq] * w2;
    f32x4 t1 = esv[kq] + ad;
    f32x4 t2 = esv[kq] * ad;
    const int u = (grp << 2) | kq;
    const int off = u * 64 + (((c16 >> 1) ^ (u & 7)) << 3) + ((c16 & 1) << 2);
    us16x4 h1, l1, h2;
#pragma unroll
    for (int c = 0; c < 4; ++c) {
      unsigned short hh = f2bf(t1[c]);
      h1[c] = hh;
      l1[c] = f2bf(t1[c] - bf2f(hh));
      h2[c] = f2bf(t2[c]);
    }
    *reinterpret_cast<us16x4*>(xw + off) = h1;
    *reinterpret_cast<us16x4*>(xw + 1024 + off) = l1;
    *reinterpret_cast<us16x4*>(xw + 2048 + off) = h2;
  }

  f32x4 acc4[4];
#pragma unroll
  for (int nt = 0; nt < 4; ++nt) acc4[nt] = (f32x4){0.f, 0.f, 0.f, 0.f};
#pragma unroll
  for (int ks = 0; ks < 2; ++ks) {
    const int aoff = r15 * 64 + (((4 * ks + g) ^ (r15 & 7)) << 3);
    short8 a1h = *(const short8*)(xw + aoff);
    short8 a1l = *(const short8*)(xw + 1024 + aoff);
    short8 a2h = *(const short8*)(xw + 2048 + aoff);
#pragma unroll
    for (int nt = 0; nt < 4; ++nt) {
      const int wb = (nt * 16 + r15) * 64 + (((4 * ks + g) ^ (r15 & 7)) << 3);
      short8 w21h = *(const short8*)(Wl + 0 * 4096 + wb);
      short8 w21l = *(const short8*)(Wl + 1 * 4096 + wb);
      short8 w22h = *(const short8*)(Wl + 2 * 4096 + wb);
      acc4[nt] = MFMA16(a1h, w21h, acc4[nt]);
      acc4[nt] = MFMA16(a1l, w21h, acc4[nt]);
      acc4[nt] = MFMA16(a1h, w21l, acc4[nt]);
      acc4[nt] = MFMA16(a2h, w22h, acc4[nt]);
    }
  }
#pragma unroll
  for (int rr = 0; rr < KQ; ++rr) {
    float ta[4], ss = 0.f;
#pragma unroll
    for (int nt = 0; nt < 4; ++nt) {
      ta[nt] = fast_tanh(acc4[nt][rr]);
      ss = fmaf(ta[nt], ta[nt], ss);
    }
    ss += __shfl_xor(ss, 1, 64); ss += __shfl_xor(ss, 2, 64);
    ss += __shfl_xor(ss, 4, 64); ss += __shfl_xor(ss, 8, 64);
    float inv = __builtin_amdgcn_rcpf(fmaxf(sqrtf(ss), 1e-12f));
#pragma unroll
    for (int nt = 0; nt < 4; ++nt) s1sum[nt] = fmaf(ta[nt], inv, s1sum[nt]);
  }
}

// ====== FULLY FUSED, W-in-LDS (VGPRs freed for gather MLP), no manual DS barriers ======
__global__ __launch_bounds__(512, 2) void hgnn_fused(
    const int* __restrict__ dsd1, const int* __restrict__ dsd2,
    const int* __restrict__ usu1, const int* __restrict__ label,
    const float* __restrict__ symp, const float* __restrict__ dise,
    const float* __restrict__ W21, const float* __restrict__ W22,
    const float* __restrict__ W11, const float* __restrict__ W12,
    const float* __restrict__ Wu, float* __restrict__ out) {
  __shared__ __align__(16) unsigned char smem[73728];
  unsigned short* Wlp = (unsigned short*)smem;             // 24 KB: {w21h, w21l, w22h}
  unsigned short* XsB = (unsigned short*)(smem + 24576);   // 48 KB, 6 KB/wave

  const int tid = threadIdx.x;
  const int lane = tid & 63;
  const int wv = __builtin_amdgcn_readfirstlane(tid >> 6);
  const int g = lane >> 4, r15 = lane & 15;
  const int grp = g, c16 = r15;
  const int bpi = (lane & 48) << 2;

  const int b0w = blockIdx.x * 32 + wv * 4;

  // ---- EARLY index preloads: all 3 steps' dsd2 quads + dsd1 + usu indices ----
  const int* d2base = dsd2 + (b0w + grp) * (K1N * K2N);
  int4 i4a = {0, 0, 0, 0}, i4b = {0, 0, 0, 0}, i4c = {0, 0, 0, 0};
  if (c16 < 10) {
    i4a = *reinterpret_cast<const int4*>(d2base + (c16 << 2));
    i4b = *reinterpret_cast<const int4*>(d2base + 40 + (c16 << 2));
  }
  if (c16 < 5) i4c = *reinterpret_cast<const int4*>(d2base + 80 + (c16 << 2));
  int sd = 0;
  if (c16 < K1N) sd = dsd1[(b0w + grp) * K1N + c16];
  int uie[4];
#pragma unroll
  for (int e = 0; e < 4; ++e) {
    int v = 0;
    if (lane < MMN) v = usu1[(b0w + e) * MMN + lane];
    uie[e] = v;
  }

  // stage 3 W planes {w21h, w21l, w22h} bf16 swizzled: 1536 chunks, 3/thread
#pragma unroll
  for (int i = 0; i < 3; ++i) {
    int c = tid + (i << 9);
    int pl = c >> 9, rc = c & 511;
    int row = rc >> 3, ch = rc & 7;
    const float* src = ((pl == 2) ? W22 : W21) + row * 64 + ch * 8;
    const bool lo = (pl == 1);
    short8 v;
#pragma unroll
    for (int j = 0; j < 8; ++j) {
      float w = src[j];
      unsigned short h = f2bf(w);
      v[j] = (short)(lo ? f2bf(w - bf2f(h)) : h);
    }
    *reinterpret_cast<short8*>(&Wlp[pl * 4096 + row * 64 + ((ch ^ (row & 7)) << 3)]) = v;
  }
  __syncthreads();

  unsigned short* xw = XsB + wv * 3072;
  float s1sum[4] = {0.f, 0.f, 0.f, 0.f};

  unsigned long long ball = __ballot((c16 < K1N) && (sd != 0));
  float c1f = (float)__popcll(ball & (1023ull << (grp << 4)));

  p1_step<4>(0, b0w, lane, grp, c16, r15, g, bpi, i4a, symp, dise, sd, Wlp, xw, s1sum);
  p1_step<4>(4, b0w, lane, grp, c16, r15, g, bpi, i4b, symp, dise, sd, Wlp, xw, s1sum);
  p1_step<2>(8, b0w, lane, grp, c16, r15, g, bpi, i4c, symp, dise, sd, Wlp, xw, s1sum);

  // s1 for elem g stays in registers (cols nt*16 + r15)
  float w1 = nb_w(c1f);
  float s1f[4];
#pragma unroll
  for (int nt = 0; nt < 4; ++nt) s1f[nt] = s1sum[nt] * w1;

  // ---- usu coda: quad-row gather, elem-interleaved (4 independent chains) ----
  const int d4 = (lane & 15) << 2;
  f32x4 su4[4];
  float cnt4[4];
#pragma unroll
  for (int e = 0; e < 4; ++e) {
    cnt4[e] = (float)__popcll(__ballot(uie[e] != 0));
    su4[e] = (f32x4){0.f, 0.f, 0.f, 0.f};
  }
#pragma unroll
  for (int m = 0; m < 48; m += 4) {
#pragma unroll
    for (int e = 0; e < 4; ++e) {
      int idx = __shfl(uie[e], m + grp, 64);
      su4[e] += *(const f32x4*)(symp + (idx << 6) + d4);  // symp row 0 is exactly zero
    }
  }
#pragma unroll
  for (int e = 0; e < 4; ++e) {
    int idx = __shfl(uie[e], 48 + grp, 64);
    if (grp < 2) su4[e] += *(const f32x4*)(symp + (idx << 6) + d4);
  }
#pragma unroll
  for (int e = 0; e < 4; ++e) {
#pragma unroll
    for (int c = 0; c < 4; ++c) {
      su4[e][c] += __shfl_xor(su4[e][c], 16, 64);
      su4[e][c] += __shfl_xor(su4[e][c], 32, 64);
    }
    su4[e] = su4[e] * nb_w(cnt4[e]);
  }

  // ================= final coda: overlay LDS, 3 matvecs + dot =================
  __syncthreads();  // everyone done with Wl/Xs before overwrite

  float4* lwf4 = (float4*)smem;               // 48 KB: W11,W12,Wu f32 swizzled
  float* xb = (float*)(smem + 49152);         // 24 KB: [8 waves][4 elems][3 planes][64]
  float* xbw = xb + wv * (4 * 3 * 64);

  // stage 3 f32 W matrices: 3072 float4 chunks, 6/thread
#pragma unroll
  for (int i = 0; i < 6; ++i) {
    int c = tid + (i << 9);
    int mt = c >> 10, rc = c & 1023;
    int e = rc >> 4, q = rc & 15;
    const float4* srcp = reinterpret_cast<const float4*>(mt == 0 ? W11 : (mt == 1 ? W12 : Wu));
    lwf4[(mt << 10) | (e << 4) | (q ^ (e & 7))] = srcp[rc];
  }
  // scatter s1 (elem g) and mu (all elems) into xb
#pragma unroll
  for (int nt = 0; nt < 4; ++nt) xbw[(g * 3 + 0) * 64 + nt * 16 + r15] = s1f[nt];
  if (lane < 16) {
#pragma unroll
    for (int e = 0; e < 4; ++e)
      *reinterpret_cast<f32x4*>(&xbw[(e * 3 + 2) * 64 + d4]) = su4[e];
  }
  __syncthreads();  // staged W visible; own-wave xb writes DS-pipe-ordered

  // x1 = s1 + t, x2 = s1 * t (lane = d)
#pragma unroll
  for (int bi = 0; bi < 4; ++bi) {
    int lb = label[b0w + bi];
    float t = dise[(lb << 6) | lane];
    float s1v = xbw[(bi * 3 + 0) * 64 + lane];
    xbw[(bi * 3 + 0) * 64 + lane] = s1v + t;
    xbw[(bi * 3 + 1) * 64 + lane] = s1v * t;
  }

  // crossbar matvec (proven round-3 final): lane = output col e
  float y1[4] = {0.f, 0.f, 0.f, 0.f};
  float y2[4] = {0.f, 0.f, 0.f, 0.f};
  const int swz = lane & 7;
#pragma unroll 4
  for (int q = 0; q < 16; ++q) {
    float4 wa = lwf4[(0 << 10) | (lane << 4) | (q ^ swz)];
    float4 wb = lwf4[(1 << 10) | (lane << 4) | (q ^ swz)];
    float4 wc = lwf4[(2 << 10) | (lane << 4) | (q ^ swz)];
#pragma unroll
    for (int bi = 0; bi < 4; ++bi) {
      float4 xv1 = *reinterpret_cast<const float4*>(&xbw[(bi * 3 + 0) * 64 + (q << 2)]);
      float4 xv2 = *reinterpret_cast<const float4*>(&xbw[(bi * 3 + 1) * 64 + (q << 2)]);
      float4 xv3 = *reinterpret_cast<const float4*>(&xbw[(bi * 3 + 2) * 64 + (q << 2)]);
      fma4(y1[bi], wa, xv1);
      fma4(y1[bi], wb, xv2);
      fma4(y2[bi], wc, xv3);
    }
  }
#pragma unroll
  for (int bi = 0; bi < 4; ++bi) {
    float p = fast_tanh(y1[bi]) * fast_tanh(y2[bi]);
#pragma unroll
    for (int off = 32; off; off >>= 1) p += __shfl_xor(p, off, 64);
    if (lane == 0) out[b0w + bi] = p;
  }
}

extern "C" void kernel_launch(void* const* d_in, const int* in_sizes, int n_in,
                              void* d_out, int out_size, void* d_ws, size_t ws_size,
                              hipStream_t stream) {
  const int* dsd1 = (const int*)d_in[0];
  const int* dsd2 = (const int*)d_in[1];
  const int* usu1 = (const int*)d_in[2];
  const int* label = (const int*)d_in[3];
  const float* symp = (const float*)d_in[4];
  const float* dise = (const float*)d_in[5];
  const float* Wu = (const float*)d_in[6];
  const float* W21 = (const float*)d_in[7];
  const float* W22 = (const float*)d_in[8];
  const float* W11 = (const float*)d_in[9];
  const float* W12 = (const float*)d_in[10];
  float* out = (float*)d_out;

  const int B = in_sizes[3];
  hipLaunchKernelGGL(hgnn_fused, dim3(B / 32), dim3(512), 0, stream,
                     dsd1, dsd2, usu1, label, symp, dise, W21, W22, W11, W12, Wu, out);
}

// Round 18
// 68.201 us; speedup vs baseline: 3.1055x; 1.0049x over previous
//
#include <hip/hip_runtime.h>
#include <hip/hip_bf16.h>

#define K1N 10
#define K2N 10
#define MMN 50

typedef __attribute__((ext_vector_type(8))) short short8;
typedef __attribute__((ext_vector_type(4))) float f32x4;
typedef __attribute__((ext_vector_type(4))) unsigned short us16x4;

__device__ __forceinline__ float fast_tanh(float x) {
  x = fminf(fmaxf(x, -15.f), 15.f);
  float e2 = __expf(2.f * x);
  return (e2 - 1.f) * __builtin_amdgcn_rcpf(e2 + 1.f);
}

// reference's _avg_on_real_neighbor weight (exact f32 semantics)
__device__ __forceinline__ float nb_w(float cnt) {
  float w = 1.0f / (cnt + 1e-8f);
  return (w >= 1e8f) ? 0.f : w;
}

// f32 -> bf16 via native cast (v_cvt_pk_bf16_f32); exact bf16 -> f32
__device__ __forceinline__ unsigned short f2bf(float x) {
  __hip_bfloat16 b = __float2bfloat16(x);
  return __builtin_bit_cast(unsigned short, b);
}
__device__ __forceinline__ float bf2f(unsigned short s) {
  return __builtin_bit_cast(float, ((unsigned)s) << 16);
}

__device__ __forceinline__ void fma4(float& y, float4 w, float4 x) {
  y = fmaf(w.x, x.x, y);
  y = fmaf(w.y, x.y, y);
  y = fmaf(w.z, x.z, y);
  y = fmaf(w.w, x.w, y);
}

#define MFMA16(A, B, C) __builtin_amdgcn_mfma_f32_16x16x32_bf16(A, B, C, 0, 0, 0)

// one phase-1 k-chunk, QUAD-ROW gather, BATCHED per-kq: all 10 bpermutes, then all
// 10 row loads into a register buffer, then tree-reduce (dep depth 4 vs 10 serial
// bpermute->load->add round-trips). W in LDS; 3 X planes {t1h,t1l,t2h}.
template <int KQ>
__device__ __forceinline__ void p1_step(
    int kbase, int b0w, int lane, int grp, int c16, int r15, int g, int bpi,
    int4 i4,
    const float* __restrict__ symp, const float* __restrict__ dise,
    int sd, const unsigned short* __restrict__ Wl,
    unsigned short* xw, float (&s1sum)[4]) {
  int idxa[4] = {i4.x, i4.y, i4.z, i4.w};

  f32x4 esv[KQ], acc[KQ];
  int c2[KQ];
  int sxv[KQ];
#pragma unroll
  for (int kq = 0; kq < KQ; ++kq)
    sxv[kq] = __builtin_amdgcn_ds_bpermute(bpi + ((kbase + kq) << 2), sd);
#pragma unroll
  for (int kq = 0; kq < KQ; ++kq)
    esv[kq] = *reinterpret_cast<const f32x4*>(symp + (sxv[kq] << 6) + (c16 << 2));

#pragma unroll
  for (int kq = 0; kq < KQ; ++kq) {
    // batch 1: all 10 index broadcasts (independent LDS ops)
    int iv[K2N];
#pragma unroll
    for (int m = 0; m < K2N; ++m) {
      const int f = kq * K2N + m;
      iv[m] = __builtin_amdgcn_ds_bpermute(bpi + ((f >> 2) << 2), idxa[f & 3]);
    }
    // batch 2: all 10 row loads into register buffer (10 in flight)
    f32x4 rb[K2N];
#pragma unroll
    for (int m = 0; m < K2N; ++m)
      rb[m] = *reinterpret_cast<const f32x4*>(dise + (iv[m] << 6) + (c16 << 2));  // row 0 = 0
    int cc = 0;
#pragma unroll
    for (int m = 0; m < K2N; ++m) cc += (iv[m] != 0);
    c2[kq] = cc;
    // tree reduce: dependency depth 4
    f32x4 s01 = rb[0] + rb[1];
    f32x4 s23 = rb[2] + rb[3];
    f32x4 s45 = rb[4] + rb[5];
    f32x4 s67 = rb[6] + rb[7];
    f32x4 s89 = rb[8] + rb[9];
    acc[kq] = ((s01 + s23) + (s45 + s67)) + s89;
  }

#pragma unroll
  for (int kq = 0; kq < KQ; ++kq) {
    float w2 = (c2[kq] == 0) ? 0.f : __builtin_amdgcn_rcpf((float)c2[kq] + 1e-8f);
    f32x4 ad = acc[kq] * w2;
    f32x4 t1 = esv[kq] + ad;
    f32x4 t2 = esv[kq] * ad;
    const int u = (grp << 2) | kq;
    const int off = u * 64 + (((c16 >> 1) ^ (u & 7)) << 3) + ((c16 & 1) << 2);
    us16x4 h1, l1, h2;
#pragma unroll
    for (int c = 0; c < 4; ++c) {
      unsigned short hh = f2bf(t1[c]);
      h1[c] = hh;
      l1[c] = f2bf(t1[c] - bf2f(hh));
      h2[c] = f2bf(t2[c]);
    }
    *reinterpret_cast<us16x4*>(xw + off) = h1;
    *reinterpret_cast<us16x4*>(xw + 1024 + off) = l1;
    *reinterpret_cast<us16x4*>(xw + 2048 + off) = h2;
  }

  f32x4 acc4[4];
#pragma unroll
  for (int nt = 0; nt < 4; ++nt) acc4[nt] = (f32x4){0.f, 0.f, 0.f, 0.f};
#pragma unroll
  for (int ks = 0; ks < 2; ++ks) {
    const int aoff = r15 * 64 + (((4 * ks + g) ^ (r15 & 7)) << 3);
    short8 a1h = *(const short8*)(xw + aoff);
    short8 a1l = *(const short8*)(xw + 1024 + aoff);
    short8 a2h = *(const short8*)(xw + 2048 + aoff);
#pragma unroll
    for (int nt = 0; nt < 4; ++nt) {
      const int wb = (nt * 16 + r15) * 64 + (((4 * ks + g) ^ (r15 & 7)) << 3);
      short8 w21h = *(const short8*)(Wl + 0 * 4096 + wb);
      short8 w21l = *(const short8*)(Wl + 1 * 4096 + wb);
      short8 w22h = *(const short8*)(Wl + 2 * 4096 + wb);
      acc4[nt] = MFMA16(a1h, w21h, acc4[nt]);
      acc4[nt] = MFMA16(a1l, w21h, acc4[nt]);
      acc4[nt] = MFMA16(a1h, w21l, acc4[nt]);
      acc4[nt] = MFMA16(a2h, w22h, acc4[nt]);
    }
  }
#pragma unroll
  for (int rr = 0; rr < KQ; ++rr) {
    float ta[4], ss = 0.f;
#pragma unroll
    for (int nt = 0; nt < 4; ++nt) {
      ta[nt] = fast_tanh(acc4[nt][rr]);
      ss = fmaf(ta[nt], ta[nt], ss);
    }
    ss += __shfl_xor(ss, 1, 64); ss += __shfl_xor(ss, 2, 64);
    ss += __shfl_xor(ss, 4, 64); ss += __shfl_xor(ss, 8, 64);
    float inv = __builtin_amdgcn_rcpf(fmaxf(sqrtf(ss), 1e-12f));
#pragma unroll
    for (int nt = 0; nt < 4; ++nt) s1sum[nt] = fmaf(ta[nt], inv, s1sum[nt]);
  }
}

// ====== FULLY FUSED, W-in-LDS, batched gather pipeline ======
__global__ __launch_bounds__(512, 2) void hgnn_fused(
    const int* __restrict__ dsd1, const int* __restrict__ dsd2,
    const int* __restrict__ usu1, const int* __restrict__ label,
    const float* __restrict__ symp, const float* __restrict__ dise,
    const float* __restrict__ W21, const float* __restrict__ W22,
    const float* __restrict__ W11, const float* __restrict__ W12,
    const float* __restrict__ Wu, float* __restrict__ out) {
  __shared__ __align__(16) unsigned char smem[73728];
  unsigned short* Wlp = (unsigned short*)smem;             // 24 KB: {w21h, w21l, w22h}
  unsigned short* XsB = (unsigned short*)(smem + 24576);   // 48 KB, 6 KB/wave

  const int tid = threadIdx.x;
  const int lane = tid & 63;
  const int wv = __builtin_amdgcn_readfirstlane(tid >> 6);
  const int g = lane >> 4, r15 = lane & 15;
  const int grp = g, c16 = r15;
  const int bpi = (lane & 48) << 2;

  const int b0w = blockIdx.x * 32 + wv * 4;

  // ---- EARLY index preloads: all 3 steps' dsd2 quads + dsd1 + usu indices ----
  const int* d2base = dsd2 + (b0w + grp) * (K1N * K2N);
  int4 i4a = {0, 0, 0, 0}, i4b = {0, 0, 0, 0}, i4c = {0, 0, 0, 0};
  if (c16 < 10) {
    i4a = *reinterpret_cast<const int4*>(d2base + (c16 << 2));
    i4b = *reinterpret_cast<const int4*>(d2base + 40 + (c16 << 2));
  }
  if (c16 < 5) i4c = *reinterpret_cast<const int4*>(d2base + 80 + (c16 << 2));
  int sd = 0;
  if (c16 < K1N) sd = dsd1[(b0w + grp) * K1N + c16];
  int uie[4];
#pragma unroll
  for (int e = 0; e < 4; ++e) {
    int v = 0;
    if (lane < MMN) v = usu1[(b0w + e) * MMN + lane];
    uie[e] = v;
  }

  // stage 3 W planes {w21h, w21l, w22h} bf16 swizzled: 1536 chunks, 3/thread
#pragma unroll
  for (int i = 0; i < 3; ++i) {
    int c = tid + (i << 9);
    int pl = c >> 9, rc = c & 511;
    int row = rc >> 3, ch = rc & 7;
    const float* src = ((pl == 2) ? W22 : W21) + row * 64 + ch * 8;
    const bool lo = (pl == 1);
    short8 v;
#pragma unroll
    for (int j = 0; j < 8; ++j) {
      float w = src[j];
      unsigned short h = f2bf(w);
      v[j] = (short)(lo ? f2bf(w - bf2f(h)) : h);
    }
    *reinterpret_cast<short8*>(&Wlp[pl * 4096 + row * 64 + ((ch ^ (row & 7)) << 3)]) = v;
  }
  __syncthreads();

  unsigned short* xw = XsB + wv * 3072;
  float s1sum[4] = {0.f, 0.f, 0.f, 0.f};

  unsigned long long ball = __ballot((c16 < K1N) && (sd != 0));
  float c1f = (float)__popcll(ball & (1023ull << (grp << 4)));

  p1_step<4>(0, b0w, lane, grp, c16, r15, g, bpi, i4a, symp, dise, sd, Wlp, xw, s1sum);
  p1_step<4>(4, b0w, lane, grp, c16, r15, g, bpi, i4b, symp, dise, sd, Wlp, xw, s1sum);
  p1_step<2>(8, b0w, lane, grp, c16, r15, g, bpi, i4c, symp, dise, sd, Wlp, xw, s1sum);

  // s1 for elem g stays in registers (cols nt*16 + r15)
  float w1 = nb_w(c1f);
  float s1f[4];
#pragma unroll
  for (int nt = 0; nt < 4; ++nt) s1f[nt] = s1sum[nt] * w1;

  // ---- usu coda: quad-row gather, elem-interleaved (4 independent chains) ----
  const int d4 = (lane & 15) << 2;
  f32x4 su4[4];
  float cnt4[4];
#pragma unroll
  for (int e = 0; e < 4; ++e) {
    cnt4[e] = (float)__popcll(__ballot(uie[e] != 0));
    su4[e] = (f32x4){0.f, 0.f, 0.f, 0.f};
  }
#pragma unroll
  for (int m = 0; m < 48; m += 4) {
#pragma unroll
    for (int e = 0; e < 4; ++e) {
      int idx = __shfl(uie[e], m + grp, 64);
      su4[e] += *(const f32x4*)(symp + (idx << 6) + d4);  // symp row 0 is exactly zero
    }
  }
#pragma unroll
  for (int e = 0; e < 4; ++e) {
    int idx = __shfl(uie[e], 48 + grp, 64);
    if (grp < 2) su4[e] += *(const f32x4*)(symp + (idx << 6) + d4);
  }
#pragma unroll
  for (int e = 0; e < 4; ++e) {
#pragma unroll
    for (int c = 0; c < 4; ++c) {
      su4[e][c] += __shfl_xor(su4[e][c], 16, 64);
      su4[e][c] += __shfl_xor(su4[e][c], 32, 64);
    }
    su4[e] = su4[e] * nb_w(cnt4[e]);
  }

  // ================= final coda: overlay LDS, 3 matvecs + dot =================
  __syncthreads();  // everyone done with Wl/Xs before overwrite

  float4* lwf4 = (float4*)smem;               // 48 KB: W11,W12,Wu f32 swizzled
  float* xb = (float*)(smem + 49152);         // 24 KB: [8 waves][4 elems][3 planes][64]
  float* xbw = xb + wv * (4 * 3 * 64);

  // stage 3 f32 W matrices: 3072 float4 chunks, 6/thread
#pragma unroll
  for (int i = 0; i < 6; ++i) {
    int c = tid + (i << 9);
    int mt = c >> 10, rc = c & 1023;
    int e = rc >> 4, q = rc & 15;
    const float4* srcp = reinterpret_cast<const float4*>(mt == 0 ? W11 : (mt == 1 ? W12 : Wu));
    lwf4[(mt << 10) | (e << 4) | (q ^ (e & 7))] = srcp[rc];
  }
  // scatter s1 (elem g) and mu (all elems) into xb
#pragma unroll
  for (int nt = 0; nt < 4; ++nt) xbw[(g * 3 + 0) * 64 + nt * 16 + r15] = s1f[nt];
  if (lane < 16) {
#pragma unroll
    for (int e = 0; e < 4; ++e)
      *reinterpret_cast<f32x4*>(&xbw[(e * 3 + 2) * 64 + d4]) = su4[e];
  }
  __syncthreads();  // staged W visible; own-wave xb writes DS-pipe-ordered

  // x1 = s1 + t, x2 = s1 * t (lane = d)
#pragma unroll
  for (int bi = 0; bi < 4; ++bi) {
    int lb = label[b0w + bi];
    float t = dise[(lb << 6) | lane];
    float s1v = xbw[(bi * 3 + 0) * 64 + lane];
    xbw[(bi * 3 + 0) * 64 + lane] = s1v + t;
    xbw[(bi * 3 + 1) * 64 + lane] = s1v * t;
  }

  // crossbar matvec (proven round-3 final): lane = output col e
  float y1[4] = {0.f, 0.f, 0.f, 0.f};
  float y2[4] = {0.f, 0.f, 0.f, 0.f};
  const int swz = lane & 7;
#pragma unroll 4
  for (int q = 0; q < 16; ++q) {
    float4 wa = lwf4[(0 << 10) | (lane << 4) | (q ^ swz)];
    float4 wb = lwf4[(1 << 10) | (lane << 4) | (q ^ swz)];
    float4 wc = lwf4[(2 << 10) | (lane << 4) | (q ^ swz)];
#pragma unroll
    for (int bi = 0; bi < 4; ++bi) {
      float4 xv1 = *reinterpret_cast<const float4*>(&xbw[(bi * 3 + 0) * 64 + (q << 2)]);
      float4 xv2 = *reinterpret_cast<const float4*>(&xbw[(bi * 3 + 1) * 64 + (q << 2)]);
      float4 xv3 = *reinterpret_cast<const float4*>(&xbw[(bi * 3 + 2) * 64 + (q << 2)]);
      fma4(y1[bi], wa, xv1);
      fma4(y1[bi], wb, xv2);
      fma4(y2[bi], wc, xv3);
    }
  }
#pragma unroll
  for (int bi = 0; bi < 4; ++bi) {
    float p = fast_tanh(y1[bi]) * fast_tanh(y2[bi]);
#pragma unroll
    for (int off = 32; off; off >>= 1) p += __shfl_xor(p, off, 64);
    if (lane == 0) out[b0w + bi] = p;
  }
}

extern "C" void kernel_launch(void* const* d_in, const int* in_sizes, int n_in,
                              void* d_out, int out_size, void* d_ws, size_t ws_size,
                              hipStream_t stream) {
  const int* dsd1 = (const int*)d_in[0];
  const int* dsd2 = (const int*)d_in[1];
  const int* usu1 = (const int*)d_in[2];
  const int* label = (const int*)d_in[3];
  const float* symp = (const float*)d_in[4];
  const float* dise = (const float*)d_in[5];
  const float* Wu = (const float*)d_in[6];
  const float* W21 = (const float*)d_in[7];
  const float* W22 = (const float*)d_in[8];
  const float* W11 = (const float*)d_in[9];
  const float* W12 = (const float*)d_in[10];
  float* out = (float*)d_out;

  const int B = in_sizes[3];
  hipLaunchKernelGGL(hgnn_fused, dim3(B / 32), dim3(512), 0, stream,
                     dsd1, dsd2, usu1, label, symp, dise, W21, W22, W11, W12, Wu, out);
}